// Round 1
// baseline (5331.874 us; speedup 1.0000x reference)
//
#include <hip/hip_runtime.h>
#include <hip/hip_bf16.h>
#include <stdint.h>

#define BB 2
#define SS 1024
#define VV 513
#define DD 512
#define HH 8
#define DKK 64
#define DFF 2048
#define LL 6

typedef __bf16 bf16x8 __attribute__((ext_vector_type(8)));
typedef float f32x4 __attribute__((ext_vector_type(4)));
typedef unsigned short us8 __attribute__((ext_vector_type(8)));
typedef unsigned short us4 __attribute__((ext_vector_type(4)));

static __device__ inline unsigned short f2bf(float f) {
  union { float f; unsigned u; } v; v.f = f;
  unsigned u = v.u;
  unsigned r = (u + 0x7FFFu + ((u >> 16) & 1u)) >> 16;
  return (unsigned short)r;
}

static __device__ inline bf16x8 ldfrag(const unsigned short* p) {
  us8 r = *(const us8*)p;
  return __builtin_bit_cast(bf16x8, r);
}

// ---------------------------------------------------------------------------
// Generic guarded GEMM: C[M,N] = A[M,K] (f32) * B[K,N] (f32), bf16 MFMA.
// Optional bias, relu, f32 out (C) and/or bf16 out (Cbf).
// Block 256 thr = 4 waves (2x2), tile 128x128, BK=32.
// ---------------------------------------------------------------------------
#define LDST 40  // LDS row stride in bf16 elems (80B: 16B-aligned, low conflict)

__global__ __launch_bounds__(256)
void gemm_kernel(const float* __restrict__ A, const float* __restrict__ Bm,
                 const float* __restrict__ bias, float* __restrict__ C,
                 unsigned short* __restrict__ Cbf,
                 int M, int N, int K, int lda, int ldb, int ldc, int relu)
{
  __shared__ unsigned short Al[128 * LDST];
  __shared__ unsigned short Bl[128 * LDST];
  const int tid = threadIdx.x;
  const int l = tid & 63, w = tid >> 6;
  const int wm = w >> 1, wn = w & 1;
  const int lr = l & 15, lg = l >> 4;
  const int m0 = blockIdx.y * 128, n0 = blockIdx.x * 128;

  f32x4 acc[4][4];
  const f32x4 zf = {0.f, 0.f, 0.f, 0.f};
#pragma unroll
  for (int i = 0; i < 4; ++i)
#pragma unroll
    for (int j = 0; j < 4; ++j) acc[i][j] = zf;

  const int nk = (K + 31) >> 5;
  for (int kt = 0; kt < nk; ++kt) {
    const int k0 = kt << 5;
    // --- stage A tile (128 x 32) ---
    {
      const int i = tid & 7, rbase = tid >> 3;
#pragma unroll
      for (int it = 0; it < 4; ++it) {
        const int row = rbase + (it << 5);
        const int grow = m0 + row;
        us4 t;
#pragma unroll
        for (int j = 0; j < 4; ++j) {
          const int gk = k0 + (i << 2) + j;
          float v = (grow < M && gk < K) ? A[(size_t)grow * lda + gk] : 0.f;
          t[j] = f2bf(v);
        }
        *(us4*)(&Al[row * LDST + (i << 2)]) = t;
      }
    }
    // --- stage B tile transposed: Bl[col][k] (128 cols x 32 k) ---
    {
      const int col = tid & 127, kg2 = tid >> 7;
      const int gcol = n0 + col;
#pragma unroll
      for (int seg = 0; seg < 2; ++seg) {
        const int kb = (((kg2 << 1) + seg) << 3);
        us8 t;
#pragma unroll
        for (int j = 0; j < 8; ++j) {
          const int gk = k0 + kb + j;
          float v = (gk < K && gcol < N) ? Bm[(size_t)gk * ldb + gcol] : 0.f;
          t[j] = f2bf(v);
        }
        *(us8*)(&Bl[col * LDST + kb]) = t;
      }
    }
    __syncthreads();
    // --- MFMA ---
    bf16x8 af[4], bfr[4];
#pragma unroll
    for (int mf = 0; mf < 4; ++mf)
      af[mf] = ldfrag(&Al[(wm * 64 + mf * 16 + lr) * LDST + (lg << 3)]);
#pragma unroll
    for (int nf = 0; nf < 4; ++nf)
      bfr[nf] = ldfrag(&Bl[(wn * 64 + nf * 16 + lr) * LDST + (lg << 3)]);
#pragma unroll
    for (int mf = 0; mf < 4; ++mf)
#pragma unroll
      for (int nf = 0; nf < 4; ++nf)
        acc[mf][nf] = __builtin_amdgcn_mfma_f32_16x16x32_bf16(af[mf], bfr[nf], acc[mf][nf], 0, 0, 0);
    __syncthreads();
  }
  // --- epilogue ---
#pragma unroll
  for (int mf = 0; mf < 4; ++mf) {
#pragma unroll
    for (int r = 0; r < 4; ++r) {
      const int grow = m0 + wm * 64 + mf * 16 + (lg << 2) + r;
      if (grow >= M) continue;
#pragma unroll
      for (int nf = 0; nf < 4; ++nf) {
        const int gcol = n0 + wn * 64 + nf * 16 + lr;
        if (gcol >= N) continue;
        float v = acc[mf][nf][r];
        if (bias) v += bias[gcol];
        if (relu) v = fmaxf(v, 0.f);
        if (C) C[(size_t)grow * ldc + gcol] = v;
        if (Cbf) Cbf[(size_t)grow * ldc + gcol] = f2bf(v);
      }
    }
  }
}

// ---------------------------------------------------------------------------
// Flash attention: Q,K,V bf16 (B*S, D) with head h at cols h*64..h*64+63.
// Block = (qt, h, b), 256 thr = 4 waves, each wave 16 q rows. f32 out.
// ---------------------------------------------------------------------------
__global__ __launch_bounds__(256)
void attn_kernel(const unsigned short* __restrict__ Qb,
                 const unsigned short* __restrict__ Kb,
                 const unsigned short* __restrict__ Vb,
                 float* __restrict__ Ob,
                 const int* __restrict__ keyvalid, int causal)
{
  __shared__ unsigned short Kl[64 * 72];
  __shared__ unsigned short Vt[64 * 72];
  __shared__ unsigned short Pl[4 * 16 * 72];
  const int tid = threadIdx.x;
  const int l = tid & 63, w = tid >> 6;
  const int qt = blockIdx.x, h = blockIdx.y, b = blockIdx.z;
  const int lr = l & 15, lg = l >> 4;
  const int qbase = qt * 64 + w * 16;

  bf16x8 qf[2];
  {
    const unsigned short* qrow = Qb + ((size_t)(b * SS) + qbase + lr) * DD + h * DKK;
    qf[0] = ldfrag(qrow + (lg << 3));
    qf[1] = ldfrag(qrow + 32 + (lg << 3));
  }

  f32x4 accO[4];
  const f32x4 zf = {0.f, 0.f, 0.f, 0.f};
#pragma unroll
  for (int i = 0; i < 4; ++i) accO[i] = zf;
  float mold[4] = {-1e30f, -1e30f, -1e30f, -1e30f};
  float lsum[4] = {0.f, 0.f, 0.f, 0.f};

  const int ktmax = causal ? (qt + 1) : (SS / 64);
  for (int kt = 0; kt < ktmax; ++kt) {
    // stage K tile [key][feat]
    {
      const int key = tid >> 2;
      const unsigned short* kr = Kb + ((size_t)(b * SS) + kt * 64 + key) * DD + h * DKK;
#pragma unroll
      for (int s2 = 0; s2 < 2; ++s2) {
        const int fg = (tid & 3) * 2 + s2;
        *(us8*)(&Kl[key * 72 + fg * 8]) = *(const us8*)(kr + fg * 8);
      }
    }
    // stage V tile transposed: Vt[d][k]
    {
      const int d = tid & 63, kg = tid >> 6;
#pragma unroll
      for (int s2 = 0; s2 < 2; ++s2) {
        const int kb = (kg + 4 * s2) << 3;
        us8 t;
#pragma unroll
        for (int j = 0; j < 8; ++j)
          t[j] = Vb[((size_t)(b * SS) + kt * 64 + kb + j) * DD + h * DKK + d];
        *(us8*)(&Vt[d * 72 + kb]) = t;
      }
    }
    __syncthreads();
    // scores S[q][key]
    float sc[4][4];
#pragma unroll
    for (int nf = 0; nf < 4; ++nf) {
      f32x4 s = zf;
      bf16x8 k0 = ldfrag(&Kl[(nf * 16 + lr) * 72 + (lg << 3)]);
      bf16x8 k1 = ldfrag(&Kl[(nf * 16 + lr) * 72 + 32 + (lg << 3)]);
      s = __builtin_amdgcn_mfma_f32_16x16x32_bf16(qf[0], k0, s, 0, 0, 0);
      s = __builtin_amdgcn_mfma_f32_16x16x32_bf16(qf[1], k1, s, 0, 0, 0);
      const int kglob = kt * 64 + nf * 16 + lr;
      const int kv = keyvalid[b * SS + kglob];
#pragma unroll
      for (int r = 0; r < 4; ++r) {
        const int qglob = qbase + (lg << 2) + r;
        const bool ok = kv && (!causal || kglob <= qglob);
        sc[nf][r] = ok ? s[r] * 0.125f : -1e9f;
      }
    }
    // online softmax per row r (rows live in 16-lane groups)
#pragma unroll
    for (int r = 0; r < 4; ++r) {
      float mloc = fmaxf(fmaxf(sc[0][r], sc[1][r]), fmaxf(sc[2][r], sc[3][r]));
#pragma unroll
      for (int off = 1; off < 16; off <<= 1)
        mloc = fmaxf(mloc, __shfl_xor(mloc, off, 64));
      const float mnew = fmaxf(mold[r], mloc);
      const float corr = __expf(mold[r] - mnew);
      float ps = 0.f;
#pragma unroll
      for (int nf = 0; nf < 4; ++nf) {
        const float p = __expf(sc[nf][r] - mnew);
        sc[nf][r] = p;
        ps += p;
      }
#pragma unroll
      for (int off = 1; off < 16; off <<= 1)
        ps += __shfl_xor(ps, off, 64);
      lsum[r] = lsum[r] * corr + ps;
#pragma unroll
      for (int nf = 0; nf < 4; ++nf) accO[nf][r] *= corr;
      mold[r] = mnew;
    }
    // P transpose via per-wave LDS region
    unsigned short* pw = &Pl[w * 16 * 72];
#pragma unroll
    for (int nf = 0; nf < 4; ++nf)
#pragma unroll
      for (int r = 0; r < 4; ++r)
        pw[((lg << 2) + r) * 72 + nf * 16 + lr] = f2bf(sc[nf][r]);
    __syncthreads();
    bf16x8 pa0 = ldfrag(&pw[lr * 72 + (lg << 3)]);
    bf16x8 pa1 = ldfrag(&pw[lr * 72 + 32 + (lg << 3)]);
#pragma unroll
    for (int nf = 0; nf < 4; ++nf) {
      bf16x8 v0 = ldfrag(&Vt[(nf * 16 + lr) * 72 + (lg << 3)]);
      bf16x8 v1 = ldfrag(&Vt[(nf * 16 + lr) * 72 + 32 + (lg << 3)]);
      accO[nf] = __builtin_amdgcn_mfma_f32_16x16x32_bf16(pa0, v0, accO[nf], 0, 0, 0);
      accO[nf] = __builtin_amdgcn_mfma_f32_16x16x32_bf16(pa1, v1, accO[nf], 0, 0, 0);
    }
    __syncthreads();
  }
#pragma unroll
  for (int r = 0; r < 4; ++r) {
    const float inv = 1.f / lsum[r];
    const size_t orow = ((size_t)(b * SS) + qbase + (lg << 2) + r) * DD + h * DKK;
#pragma unroll
    for (int nf = 0; nf < 4; ++nf)
      Ob[orow + nf * 16 + lr] = accO[nf][r] * inv;
  }
}

// ---------------------------------------------------------------------------
// out = LN(a + c) * g + b     (one wave per row, D=512)
// ---------------------------------------------------------------------------
__global__ __launch_bounds__(64)
void addln_kernel(const float* __restrict__ a, const float* __restrict__ c,
                  const float* __restrict__ g, const float* __restrict__ bb,
                  float* __restrict__ out)
{
  const int row = blockIdx.x, l = threadIdx.x;
  const float* ar = a + (size_t)row * DD;
  const float* cr = c + (size_t)row * DD;
  float x[8];
  float sum = 0.f;
#pragma unroll
  for (int j = 0; j < 8; ++j) { x[j] = ar[l + 64 * j] + cr[l + 64 * j]; sum += x[j]; }
#pragma unroll
  for (int off = 1; off < 64; off <<= 1) sum += __shfl_xor(sum, off, 64);
  const float mean = sum * (1.f / 512.f);
  float vs = 0.f;
#pragma unroll
  for (int j = 0; j < 8; ++j) { const float d = x[j] - mean; vs += d * d; }
#pragma unroll
  for (int off = 1; off < 64; off <<= 1) vs += __shfl_xor(vs, off, 64);
  const float rs = rsqrtf(vs * (1.f / 512.f) + 1e-6f);
  float* orow = out + (size_t)row * DD;
#pragma unroll
  for (int j = 0; j < 8; ++j) {
    const int col = l + 64 * j;
    orow[col] = (x[j] - mean) * rs * g[col] + bb[col];
  }
}

__global__ __launch_bounds__(64)
void rowvalid_kernel(const float* __restrict__ x, int n, int* __restrict__ out)
{
  const int row = blockIdx.x, l = threadIdx.x;
  const float* xr = x + (size_t)row * n;
  int ok = 1;
  for (int j = l; j < n; j += 64) ok &= (xr[j] != -1.0f) ? 1 : 0;
  ok = __all(ok) ? 1 : 0;
  if (l == 0) out[row] = ok;
}

__global__ void postable_kernel(float* __restrict__ tab)
{
  const int i = blockIdx.x * blockDim.x + threadIdx.x;
  if (i >= SS * DD) return;
  const int s = i >> 9, d = i & 511;
  const float ex = (float)(2 * (d >> 1)) * (1.0f / (float)DD);
  const float ang = (float)s * powf(10000.0f, -ex);
  tab[i] = (d & 1) ? cosf(ang) : sinf(ang);
}

__global__ void gpec_kernel(const float* __restrict__ gk, float* __restrict__ Mb)
{
  const int i = blockIdx.x * blockDim.x + threadIdx.x;
  if (i >= BB * SS * SS) return;
  const int b = i / (SS * SS);
  const int rem = i - b * (SS * SS);
  const float* p = gk + (size_t)b * 3 * SS * SS + rem;
  Mb[i] = (p[0] + 0.9f * p[SS * SS] + 0.81f * p[2 * SS * SS]) * (1.0f / 2.71f);
}

// ---------------------------------------------------------------------------
static inline void gemm(hipStream_t s, const float* A, const float* B,
                        const float* bias, float* C, unsigned short* Cbf,
                        int M, int N, int K, int lda, int ldb, int ldc, int relu)
{
  dim3 g((N + 127) / 128, (M + 127) / 128), b(256);
  gemm_kernel<<<g, b, 0, s>>>(A, B, bias, C, Cbf, M, N, K, lda, ldb, ldc, relu);
}

extern "C" void kernel_launch(void* const* d_in, const int* in_sizes, int n_in,
                              void* d_out, int out_size, void* d_ws, size_t ws_size,
                              hipStream_t stream)
{
  (void)in_sizes; (void)n_in; (void)out_size; (void)ws_size;
  const float* dec_in = (const float*)d_in[0];
  const float* prev   = (const float*)d_in[1];
  const float* gk     = (const float*)d_in[6];
  const float* emb_w1 = (const float*)d_in[7];
  const float* emb_b1 = (const float*)d_in[8];
  const float* emb_w2 = (const float*)d_in[9];
  const float* emb_b2 = (const float*)d_in[10];
  const float* emb_w3 = (const float*)d_in[11];
  const float* emb_b3 = (const float*)d_in[12];
  const float* ln0_g  = (const float*)d_in[13];
  const float* ln0_b  = (const float*)d_in[14];
  const float* wq     = (const float*)d_in[15];
  const float* wk     = (const float*)d_in[16];
  const float* wv     = (const float*)d_in[17];
  const float* wo     = (const float*)d_in[18];
  const float* cq     = (const float*)d_in[19];
  const float* ck     = (const float*)d_in[20];
  const float* cv     = (const float*)d_in[21];
  const float* co     = (const float*)d_in[22];
  const float* ffn_w1 = (const float*)d_in[23];
  const float* ffn_w2 = (const float*)d_in[24];
  const float* ffn_b1 = (const float*)d_in[25];
  const float* ffn_b2 = (const float*)d_in[26];
  const float* ln1_g  = (const float*)d_in[27];
  const float* ln1_b  = (const float*)d_in[28];
  const float* ln2_g  = (const float*)d_in[29];
  const float* ln2_b  = (const float*)d_in[30];
  const float* ln3_g  = (const float*)d_in[31];
  const float* ln3_b  = (const float*)d_in[32];
  const float* p_w1   = (const float*)d_in[33];
  const float* p_b1   = (const float*)d_in[34];
  const float* p_w2   = (const float*)d_in[35];
  const float* p_b2   = (const float*)d_in[36];
  const float* p_w3   = (const float*)d_in[37];
  const float* p_b3   = (const float*)d_in[38];

  // workspace layout
  char* ws = (char*)d_ws;
  float* postab = (float*)ws;  ws += (size_t)SS * DD * 4;          // 2 MB
  float* Mb     = (float*)ws;  ws += (size_t)BB * SS * SS * 4;     // 8 MB
  float* h      = (float*)ws;  ws += (size_t)BB * SS * DD * 4;     // 4 MB
  float* t1     = (float*)ws;  ws += (size_t)BB * SS * DFF * 4;    // 16 MB
  float* t2     = (float*)ws;  ws += (size_t)BB * SS * DFF * 4;    // 16 MB
  float* attno  = (float*)ws;  ws += (size_t)BB * SS * DD * 4;     // 4 MB
  unsigned short* qb = (unsigned short*)ws; ws += (size_t)BB * SS * DD * 2;
  unsigned short* kb = (unsigned short*)ws; ws += (size_t)BB * SS * DD * 2;
  unsigned short* vb = (unsigned short*)ws; ws += (size_t)BB * SS * DD * 2;
  int* kvs = (int*)ws; ws += (size_t)BB * SS * 4;
  int* kve = (int*)ws; ws += (size_t)BB * SS * 4;

  const int M = BB * SS;  // 2048

  // prep
  rowvalid_kernel<<<M, 64, 0, stream>>>(dec_in, VV, kvs);
  rowvalid_kernel<<<M, 64, 0, stream>>>(prev, DD, kve);
  postable_kernel<<<(SS * DD + 255) / 256, 256, 0, stream>>>(postab);
  gpec_kernel<<<(BB * SS * SS + 255) / 256, 256, 0, stream>>>(gk, Mb);

  // embedding MLP
  gemm(stream, dec_in, emb_w1, emb_b1, t1, nullptr, M, VV, VV, VV, VV, VV, 1);
  gemm(stream, t1, emb_w2, emb_b2, t2, nullptr, M, VV, VV, VV, VV, VV, 1);
  gemm(stream, t2, emb_w3, emb_b3, h, nullptr, M, DD, VV, VV, DD, DD, 0);
  // graph positional encoding: (M x S) @ (S x D)
  gemm(stream, Mb, postab, nullptr, t1, nullptr, M, DD, SS, SS, DD, DD, 0);
  addln_kernel<<<M, 64, 0, stream>>>(h, t1, ln0_g, ln0_b, h);

  for (int i = 0; i < LL; ++i) {
    const size_t od = (size_t)i * DD * DD;
    // self attention
    gemm(stream, h, wq + od, nullptr, nullptr, qb, M, DD, DD, DD, DD, DD, 0);
    gemm(stream, h, wk + od, nullptr, nullptr, kb, M, DD, DD, DD, DD, DD, 0);
    gemm(stream, h, wv + od, nullptr, nullptr, vb, M, DD, DD, DD, DD, DD, 0);
    attn_kernel<<<dim3(SS / 64, HH, BB), 256, 0, stream>>>(qb, kb, vb, attno, kvs, 1);
    gemm(stream, attno, wo + od, nullptr, t1, nullptr, M, DD, DD, DD, DD, DD, 0);
    addln_kernel<<<M, 64, 0, stream>>>(h, t1, ln1_g + i * DD, ln1_b + i * DD, h);
    // cross attention
    gemm(stream, h, cq + od, nullptr, nullptr, qb, M, DD, DD, DD, DD, DD, 0);
    gemm(stream, prev, ck + od, nullptr, nullptr, kb, M, DD, DD, DD, DD, DD, 0);
    gemm(stream, prev, cv + od, nullptr, nullptr, vb, M, DD, DD, DD, DD, DD, 0);
    attn_kernel<<<dim3(SS / 64, HH, BB), 256, 0, stream>>>(qb, kb, vb, attno, kve, 0);
    gemm(stream, attno, co + od, nullptr, t1, nullptr, M, DD, DD, DD, DD, DD, 0);
    addln_kernel<<<M, 64, 0, stream>>>(h, t1, ln2_g + i * DD, ln2_b + i * DD, h);
    // FFN
    gemm(stream, h, ffn_w1 + (size_t)i * DD * DFF, ffn_b1 + i * DFF, t1, nullptr,
         M, DFF, DD, DD, DFF, DFF, 1);
    gemm(stream, t1, ffn_w2 + (size_t)i * DFF * DD, ffn_b2 + i * DD, t2, nullptr,
         M, DD, DFF, DFF, DD, DD, 0);
    addln_kernel<<<M, 64, 0, stream>>>(h, t2, ln3_g + i * DD, ln3_b + i * DD, h);
  }

  // output head
  gemm(stream, h, p_w1, p_b1, t1, nullptr, M, VV, DD, DD, VV, VV, 1);
  gemm(stream, t1, p_w2, p_b2, t2, nullptr, M, VV, VV, VV, VV, VV, 1);
  gemm(stream, t2, p_w3, p_b3, (float*)d_out, nullptr, M, VV, VV, VV, VV, VV, 0);
}

// Round 2
// 3341.978 us; speedup vs baseline: 1.5954x; 1.5954x over previous
//
#include <hip/hip_runtime.h>
#include <hip/hip_bf16.h>
#include <stdint.h>

#define BB 2
#define SS 1024
#define VV 513
#define DD 512
#define HH 8
#define DKK 64
#define DFF 2048
#define LL 6

typedef __bf16 bf16x8 __attribute__((ext_vector_type(8)));
typedef float f32x4 __attribute__((ext_vector_type(4)));
typedef unsigned short us8 __attribute__((ext_vector_type(8)));
typedef unsigned short us4 __attribute__((ext_vector_type(4)));
typedef unsigned short us2 __attribute__((ext_vector_type(2)));

static __device__ inline unsigned short f2bf(float f) {
  union { float f; unsigned u; } v; v.f = f;
  unsigned u = v.u;
  unsigned r = (u + 0x7FFFu + ((u >> 16) & 1u)) >> 16;
  return (unsigned short)r;
}

static __device__ inline bf16x8 ldfrag(const unsigned short* p) {
  us8 r = *(const us8*)p;
  return __builtin_bit_cast(bf16x8, r);
}

// ---------------------------------------------------------------------------
// Templated guarded GEMM: C = A[M,K](f32) * B[K,N](f32), bf16 MFMA.
// 256 thr = 4 waves in 2x2. NB = number of fused (B, out) pairs sharing A.
// ---------------------------------------------------------------------------
struct GemmP {
  const float* A;
  const float* B0; const float* B1; const float* B2;
  const float* bias;
  float* C0; float* C1; float* C2;
  unsigned short* D0; unsigned short* D1; unsigned short* D2;
  int M, N, K, lda, ldb, ldc, relu;
};

template<int BM, int BN, int BK, int NB>
__global__ __launch_bounds__(256)
void gemm_tpl(GemmP p)
{
  constexpr int LDST = BK + 8;          // bf16 elems; byte stride BK*2+16
  constexpr int WM = BM / 2, WN = BN / 2;
  constexpr int FM = WM / 16, FN = WN / 16;
  constexpr int KS = BK / 32;
  __shared__ unsigned short Al[BM * LDST];
  __shared__ unsigned short Bl[BN * LDST];
  const int tid = threadIdx.x;
  const int l = tid & 63, w = tid >> 6;
  const int wm = w >> 1, wn = w & 1;
  const int lr = l & 15, lg = l >> 4;

  const int nbn = (p.N + BN - 1) / BN;
  int sel = 0, bx = blockIdx.x;
  if (NB > 1) { sel = bx / nbn; bx -= sel * nbn; }
  const float* Bmat = p.B0;
  if (NB > 1 && sel == 1) Bmat = p.B1;
  if (NB > 2 && sel == 2) Bmat = p.B2;
  const int m0 = blockIdx.y * BM, n0 = bx * BN;

  f32x4 acc[FM][FN];
  const f32x4 zf = {0.f, 0.f, 0.f, 0.f};
#pragma unroll
  for (int i = 0; i < FM; ++i)
#pragma unroll
    for (int j = 0; j < FN; ++j) acc[i][j] = zf;

  const int nk = (p.K + BK - 1) / BK;
  for (int kt = 0; kt < nk; ++kt) {
    const int k0 = kt * BK;
    // --- stage A (BM x BK): lane-coalesced, 2 consecutive k per lane ---
    {
      constexpr int PA = BM * BK / 512;
#pragma unroll
      for (int ps = 0; ps < PA; ++ps) {
        const int idx2 = ps * 256 + tid;
        const int row = idx2 / (BK / 2);
        const int k2 = (idx2 % (BK / 2)) << 1;
        const int grow = m0 + row;
        const int gk = k0 + k2;
        const float* ap = p.A + (size_t)grow * p.lda + gk;
        us2 t;
        t[0] = (grow < p.M && gk     < p.K) ? f2bf(ap[0]) : (unsigned short)0;
        t[1] = (grow < p.M && gk + 1 < p.K) ? f2bf(ap[1]) : (unsigned short)0;
        *(us2*)(&Al[row * LDST + k2]) = t;
      }
    }
    // --- stage B transposed: Bl[col][k] ---
    {
      constexpr int TPC = 256 / BN;    // threads per col
      constexpr int KPT = BK / TPC;    // k per thread (16)
      const int col = tid % BN, kg = tid / BN;
      const int gcol = n0 + col;
      const bool colok = gcol < p.N;
#pragma unroll
      for (int c = 0; c < KPT / 8; ++c) {
        us8 t;
#pragma unroll
        for (int j = 0; j < 8; ++j) {
          const int gk = k0 + kg * KPT + c * 8 + j;
          const float v = (colok && gk < p.K) ? Bmat[(size_t)gk * p.ldb + gcol] : 0.f;
          t[j] = f2bf(v);
        }
        *(us8*)(&Bl[col * LDST + kg * KPT + c * 8]) = t;
      }
    }
    __syncthreads();
#pragma unroll
    for (int ks = 0; ks < KS; ++ks) {
      bf16x8 af[FM], bfv[FN];
#pragma unroll
      for (int mf = 0; mf < FM; ++mf)
        af[mf] = ldfrag(&Al[(wm * WM + mf * 16 + lr) * LDST + ks * 32 + (lg << 3)]);
#pragma unroll
      for (int nf = 0; nf < FN; ++nf)
        bfv[nf] = ldfrag(&Bl[(wn * WN + nf * 16 + lr) * LDST + ks * 32 + (lg << 3)]);
#pragma unroll
      for (int mf = 0; mf < FM; ++mf)
#pragma unroll
        for (int nf = 0; nf < FN; ++nf)
          acc[mf][nf] = __builtin_amdgcn_mfma_f32_16x16x32_bf16(af[mf], bfv[nf], acc[mf][nf], 0, 0, 0);
    }
    __syncthreads();
  }
  // --- epilogue ---
  float* Csel = p.C0;
  unsigned short* Dsel = p.D0;
  if (NB > 1 && sel == 1) { Csel = p.C1; Dsel = p.D1; }
  if (NB > 2 && sel == 2) { Csel = p.C2; Dsel = p.D2; }
#pragma unroll
  for (int mf = 0; mf < FM; ++mf) {
#pragma unroll
    for (int r = 0; r < 4; ++r) {
      const int grow = m0 + wm * WM + mf * 16 + (lg << 2) + r;
      if (grow >= p.M) continue;
#pragma unroll
      for (int nf = 0; nf < FN; ++nf) {
        const int gcol = n0 + wn * WN + nf * 16 + lr;
        if (gcol >= p.N) continue;
        float v = acc[mf][nf][r];
        if (p.bias) v += p.bias[gcol];
        if (p.relu) v = fmaxf(v, 0.f);
        if (Csel) Csel[(size_t)grow * p.ldc + gcol] = v;
        if (Dsel) Dsel[(size_t)grow * p.ldc + gcol] = f2bf(v);
      }
    }
  }
}

// ---------------------------------------------------------------------------
// Flash attention: Q,K,V bf16 (B*S, D), head h at cols h*64..h*64+63.
// ---------------------------------------------------------------------------
__global__ __launch_bounds__(256)
void attn_kernel(const unsigned short* __restrict__ Qb,
                 const unsigned short* __restrict__ Kb,
                 const unsigned short* __restrict__ Vb,
                 float* __restrict__ Ob,
                 const int* __restrict__ keyvalid, int causal)
{
  __shared__ unsigned short Kl[64 * 72];
  __shared__ unsigned short Vt[64 * 72];
  __shared__ unsigned short Pl[4 * 16 * 72];
  const int tid = threadIdx.x;
  const int l = tid & 63, w = tid >> 6;
  const int qt = blockIdx.x, h = blockIdx.y, b = blockIdx.z;
  const int lr = l & 15, lg = l >> 4;
  const int qbase = qt * 64 + w * 16;

  bf16x8 qf[2];
  {
    const unsigned short* qrow = Qb + ((size_t)(b * SS) + qbase + lr) * DD + h * DKK;
    qf[0] = ldfrag(qrow + (lg << 3));
    qf[1] = ldfrag(qrow + 32 + (lg << 3));
  }

  f32x4 accO[4];
  const f32x4 zf = {0.f, 0.f, 0.f, 0.f};
#pragma unroll
  for (int i = 0; i < 4; ++i) accO[i] = zf;
  float mold[4] = {-1e30f, -1e30f, -1e30f, -1e30f};
  float lsum[4] = {0.f, 0.f, 0.f, 0.f};

  const int ktmax = causal ? (qt + 1) : (SS / 64);
  for (int kt = 0; kt < ktmax; ++kt) {
    {
      const int key = tid >> 2;
      const unsigned short* kr = Kb + ((size_t)(b * SS) + kt * 64 + key) * DD + h * DKK;
#pragma unroll
      for (int s2 = 0; s2 < 2; ++s2) {
        const int fg = (tid & 3) * 2 + s2;
        *(us8*)(&Kl[key * 72 + fg * 8]) = *(const us8*)(kr + fg * 8);
      }
    }
    {
      const int d = tid & 63, kg = tid >> 6;
#pragma unroll
      for (int s2 = 0; s2 < 2; ++s2) {
        const int kb = (kg + 4 * s2) << 3;
        us8 t;
#pragma unroll
        for (int j = 0; j < 8; ++j)
          t[j] = Vb[((size_t)(b * SS) + kt * 64 + kb + j) * DD + h * DKK + d];
        *(us8*)(&Vt[d * 72 + kb]) = t;
      }
    }
    __syncthreads();
    float sc[4][4];
#pragma unroll
    for (int nf = 0; nf < 4; ++nf) {
      f32x4 s = zf;
      bf16x8 k0 = ldfrag(&Kl[(nf * 16 + lr) * 72 + (lg << 3)]);
      bf16x8 k1 = ldfrag(&Kl[(nf * 16 + lr) * 72 + 32 + (lg << 3)]);
      s = __builtin_amdgcn_mfma_f32_16x16x32_bf16(qf[0], k0, s, 0, 0, 0);
      s = __builtin_amdgcn_mfma_f32_16x16x32_bf16(qf[1], k1, s, 0, 0, 0);
      const int kglob = kt * 64 + nf * 16 + lr;
      const int kv = keyvalid[b * SS + kglob];
#pragma unroll
      for (int r = 0; r < 4; ++r) {
        const int qglob = qbase + (lg << 2) + r;
        const bool ok = kv && (!causal || kglob <= qglob);
        sc[nf][r] = ok ? s[r] * 0.125f : -1e9f;
      }
    }
#pragma unroll
    for (int r = 0; r < 4; ++r) {
      float mloc = fmaxf(fmaxf(sc[0][r], sc[1][r]), fmaxf(sc[2][r], sc[3][r]));
#pragma unroll
      for (int off = 1; off < 16; off <<= 1)
        mloc = fmaxf(mloc, __shfl_xor(mloc, off, 64));
      const float mnew = fmaxf(mold[r], mloc);
      const float corr = __expf(mold[r] - mnew);
      float ps = 0.f;
#pragma unroll
      for (int nf = 0; nf < 4; ++nf) {
        const float pv = __expf(sc[nf][r] - mnew);
        sc[nf][r] = pv;
        ps += pv;
      }
#pragma unroll
      for (int off = 1; off < 16; off <<= 1)
        ps += __shfl_xor(ps, off, 64);
      lsum[r] = lsum[r] * corr + ps;
#pragma unroll
      for (int nf = 0; nf < 4; ++nf) accO[nf][r] *= corr;
      mold[r] = mnew;
    }
    unsigned short* pw = &Pl[w * 16 * 72];
#pragma unroll
    for (int nf = 0; nf < 4; ++nf)
#pragma unroll
      for (int r = 0; r < 4; ++r)
        pw[((lg << 2) + r) * 72 + nf * 16 + lr] = f2bf(sc[nf][r]);
    __syncthreads();
    bf16x8 pa0 = ldfrag(&pw[lr * 72 + (lg << 3)]);
    bf16x8 pa1 = ldfrag(&pw[lr * 72 + 32 + (lg << 3)]);
#pragma unroll
    for (int nf = 0; nf < 4; ++nf) {
      bf16x8 v0 = ldfrag(&Vt[(nf * 16 + lr) * 72 + (lg << 3)]);
      bf16x8 v1 = ldfrag(&Vt[(nf * 16 + lr) * 72 + 32 + (lg << 3)]);
      accO[nf] = __builtin_amdgcn_mfma_f32_16x16x32_bf16(pa0, v0, accO[nf], 0, 0, 0);
      accO[nf] = __builtin_amdgcn_mfma_f32_16x16x32_bf16(pa1, v1, accO[nf], 0, 0, 0);
    }
    __syncthreads();
  }
#pragma unroll
  for (int r = 0; r < 4; ++r) {
    const float inv = 1.f / lsum[r];
    const size_t orow = ((size_t)(b * SS) + qbase + (lg << 2) + r) * DD + h * DKK;
#pragma unroll
    for (int nf = 0; nf < 4; ++nf)
      Ob[orow + nf * 16 + lr] = accO[nf][r] * inv;
  }
}

// ---------------------------------------------------------------------------
__global__ __launch_bounds__(64)
void addln_kernel(const float* __restrict__ a, const float* __restrict__ c,
                  const float* __restrict__ g, const float* __restrict__ bb,
                  float* __restrict__ out)
{
  const int row = blockIdx.x, l = threadIdx.x;
  const float* ar = a + (size_t)row * DD;
  const float* cr = c + (size_t)row * DD;
  float x[8];
  float sum = 0.f;
#pragma unroll
  for (int j = 0; j < 8; ++j) { x[j] = ar[l + 64 * j] + cr[l + 64 * j]; sum += x[j]; }
#pragma unroll
  for (int off = 1; off < 64; off <<= 1) sum += __shfl_xor(sum, off, 64);
  const float mean = sum * (1.f / 512.f);
  float vs = 0.f;
#pragma unroll
  for (int j = 0; j < 8; ++j) { const float d = x[j] - mean; vs += d * d; }
#pragma unroll
  for (int off = 1; off < 64; off <<= 1) vs += __shfl_xor(vs, off, 64);
  const float rs = rsqrtf(vs * (1.f / 512.f) + 1e-6f);
  float* orow = out + (size_t)row * DD;
#pragma unroll
  for (int j = 0; j < 8; ++j) {
    const int col = l + 64 * j;
    orow[col] = (x[j] - mean) * rs * g[col] + bb[col];
  }
}

__global__ __launch_bounds__(64)
void rowvalid_kernel(const float* __restrict__ x, int n, int* __restrict__ out)
{
  const int row = blockIdx.x, l = threadIdx.x;
  const float* xr = x + (size_t)row * n;
  int ok = 1;
  for (int j = l; j < n; j += 64) ok &= (xr[j] != -1.0f) ? 1 : 0;
  ok = __all(ok) ? 1 : 0;
  if (l == 0) out[row] = ok;
}

__global__ void postable_kernel(float* __restrict__ tab)
{
  const int i = blockIdx.x * blockDim.x + threadIdx.x;
  if (i >= SS * DD) return;
  const int s = i >> 9, d = i & 511;
  const float ex = (float)(2 * (d >> 1)) * (1.0f / (float)DD);
  const float ang = (float)s * powf(10000.0f, -ex);
  tab[i] = (d & 1) ? cosf(ang) : sinf(ang);
}

__global__ void gpec_kernel(const float* __restrict__ gk, float* __restrict__ Mb)
{
  const int i = blockIdx.x * blockDim.x + threadIdx.x;
  if (i >= BB * SS * SS) return;
  const int b = i / (SS * SS);
  const int rem = i - b * (SS * SS);
  const float* p = gk + (size_t)b * 3 * SS * SS + rem;
  Mb[i] = (p[0] + 0.9f * p[SS * SS] + 0.81f * p[2 * SS * SS]) * (1.0f / 2.71f);
}

// ---------------------------------------------------------------------------
static inline GemmP mkp(const float* A, const float* B, const float* bias,
                        float* C, unsigned short* D,
                        int M, int N, int K, int lda, int ldb, int ldc, int relu)
{
  GemmP p{};
  p.A = A; p.B0 = B; p.bias = bias; p.C0 = C; p.D0 = D;
  p.M = M; p.N = N; p.K = K; p.lda = lda; p.ldb = ldb; p.ldc = ldc; p.relu = relu;
  return p;
}

static inline void g1(hipStream_t s, const float* A, const float* B, const float* bias,
                      float* C, unsigned short* D,
                      int M, int N, int K, int lda, int ldb, int ldc, int relu)
{
  GemmP p = mkp(A, B, bias, C, D, M, N, K, lda, ldb, ldc, relu);
  dim3 g((N + 63) / 64, (M + 63) / 64);
  gemm_tpl<64, 64, 64, 1><<<g, 256, 0, s>>>(p);
}

static inline void g2(hipStream_t s, const float* A, const float* B0, const float* B1,
                      unsigned short* D0, unsigned short* D1,
                      int M, int N, int K, int lda, int ldb, int ldc)
{
  GemmP p = mkp(A, B0, nullptr, nullptr, D0, M, N, K, lda, ldb, ldc, 0);
  p.B1 = B1; p.D1 = D1;
  const int nbn = (N + 63) / 64;
  dim3 g(2 * nbn, (M + 63) / 64);
  gemm_tpl<64, 64, 64, 2><<<g, 256, 0, s>>>(p);
}

static inline void g3(hipStream_t s, const float* A, const float* B0, const float* B1,
                      const float* B2, unsigned short* D0, unsigned short* D1,
                      unsigned short* D2, int M, int N, int K, int lda, int ldb, int ldc)
{
  GemmP p = mkp(A, B0, nullptr, nullptr, D0, M, N, K, lda, ldb, ldc, 0);
  p.B1 = B1; p.D1 = D1; p.B2 = B2; p.D2 = D2;
  const int nbn = (N + 63) / 64;
  dim3 g(3 * nbn, (M + 63) / 64);
  gemm_tpl<64, 64, 64, 3><<<g, 256, 0, s>>>(p);
}

extern "C" void kernel_launch(void* const* d_in, const int* in_sizes, int n_in,
                              void* d_out, int out_size, void* d_ws, size_t ws_size,
                              hipStream_t stream)
{
  (void)in_sizes; (void)n_in; (void)out_size; (void)ws_size;
  const float* dec_in = (const float*)d_in[0];
  const float* prev   = (const float*)d_in[1];
  const float* gk     = (const float*)d_in[6];
  const float* emb_w1 = (const float*)d_in[7];
  const float* emb_b1 = (const float*)d_in[8];
  const float* emb_w2 = (const float*)d_in[9];
  const float* emb_b2 = (const float*)d_in[10];
  const float* emb_w3 = (const float*)d_in[11];
  const float* emb_b3 = (const float*)d_in[12];
  const float* ln0_g  = (const float*)d_in[13];
  const float* ln0_b  = (const float*)d_in[14];
  const float* wq     = (const float*)d_in[15];
  const float* wk     = (const float*)d_in[16];
  const float* wv     = (const float*)d_in[17];
  const float* wo     = (const float*)d_in[18];
  const float* cq     = (const float*)d_in[19];
  const float* ck     = (const float*)d_in[20];
  const float* cv     = (const float*)d_in[21];
  const float* co     = (const float*)d_in[22];
  const float* ffn_w1 = (const float*)d_in[23];
  const float* ffn_w2 = (const float*)d_in[24];
  const float* ffn_b1 = (const float*)d_in[25];
  const float* ffn_b2 = (const float*)d_in[26];
  const float* ln1_g  = (const float*)d_in[27];
  const float* ln1_b  = (const float*)d_in[28];
  const float* ln2_g  = (const float*)d_in[29];
  const float* ln2_b  = (const float*)d_in[30];
  const float* ln3_g  = (const float*)d_in[31];
  const float* ln3_b  = (const float*)d_in[32];
  const float* p_w1   = (const float*)d_in[33];
  const float* p_b1   = (const float*)d_in[34];
  const float* p_w2   = (const float*)d_in[35];
  const float* p_b2   = (const float*)d_in[36];
  const float* p_w3   = (const float*)d_in[37];
  const float* p_b3   = (const float*)d_in[38];

  // workspace layout
  char* ws = (char*)d_ws;
  float* postab = (float*)ws;  ws += (size_t)SS * DD * 4;
  float* Mb     = (float*)ws;  ws += (size_t)BB * SS * SS * 4;
  float* h      = (float*)ws;  ws += (size_t)BB * SS * DD * 4;
  float* t1     = (float*)ws;  ws += (size_t)BB * SS * DFF * 4;
  float* t2     = (float*)ws;  ws += (size_t)BB * SS * DFF * 4;
  float* attno  = (float*)ws;  ws += (size_t)BB * SS * DD * 4;
  unsigned short* qb = (unsigned short*)ws; ws += (size_t)BB * SS * DD * 2;
  unsigned short* kb = (unsigned short*)ws; ws += (size_t)BB * SS * DD * 2;
  unsigned short* vb = (unsigned short*)ws; ws += (size_t)BB * SS * DD * 2;
  int* kvs = (int*)ws; ws += (size_t)BB * SS * 4;
  int* kve = (int*)ws; ws += (size_t)BB * SS * 4;

  const int M = BB * SS;  // 2048

  // prep
  rowvalid_kernel<<<M, 64, 0, stream>>>(dec_in, VV, kvs);
  rowvalid_kernel<<<M, 64, 0, stream>>>(prev, DD, kve);
  postable_kernel<<<(SS * DD + 255) / 256, 256, 0, stream>>>(postab);
  gpec_kernel<<<(BB * SS * SS + 255) / 256, 256, 0, stream>>>(gk, Mb);

  // embedding MLP
  g1(stream, dec_in, emb_w1, emb_b1, t1, nullptr, M, VV, VV, VV, VV, VV, 1);
  g1(stream, t1, emb_w2, emb_b2, t2, nullptr, M, VV, VV, VV, VV, VV, 1);
  g1(stream, t2, emb_w3, emb_b3, h, nullptr, M, DD, VV, VV, DD, DD, 0);
  // graph positional encoding: (M x S) @ (S x D)
  g1(stream, Mb, postab, nullptr, t1, nullptr, M, DD, SS, SS, DD, DD, 0);
  addln_kernel<<<M, 64, 0, stream>>>(h, t1, ln0_g, ln0_b, h);

  for (int i = 0; i < LL; ++i) {
    const size_t od = (size_t)i * DD * DD;
    // self attention (fused QKV)
    g3(stream, h, wq + od, wk + od, wv + od, qb, kb, vb, M, DD, DD, DD, DD, DD);
    attn_kernel<<<dim3(SS / 64, HH, BB), 256, 0, stream>>>(qb, kb, vb, attno, kvs, 1);
    g1(stream, attno, wo + od, nullptr, t1, nullptr, M, DD, DD, DD, DD, DD, 0);
    addln_kernel<<<M, 64, 0, stream>>>(h, t1, ln1_g + i * DD, ln1_b + i * DD, h);
    // cross attention (fused KV on prev)
    g1(stream, h, cq + od, nullptr, nullptr, qb, M, DD, DD, DD, DD, DD, 0);
    g2(stream, prev, ck + od, cv + od, kb, vb, M, DD, DD, DD, DD, DD);
    attn_kernel<<<dim3(SS / 64, HH, BB), 256, 0, stream>>>(qb, kb, vb, attno, kve, 0);
    g1(stream, attno, co + od, nullptr, t1, nullptr, M, DD, DD, DD, DD, DD, 0);
    addln_kernel<<<M, 64, 0, stream>>>(h, t1, ln2_g + i * DD, ln2_b + i * DD, h);
    // FFN
    g1(stream, h, ffn_w1 + (size_t)i * DD * DFF, ffn_b1 + i * DFF, t1, nullptr,
       M, DFF, DD, DD, DFF, DFF, 1);
    g1(stream, t1, ffn_w2 + (size_t)i * DFF * DD, ffn_b2 + i * DD, t2, nullptr,
       M, DD, DFF, DFF, DD, DD, 0);
    addln_kernel<<<M, 64, 0, stream>>>(h, t2, ln3_g + i * DD, ln3_b + i * DD, h);
  }

  // output head
  g1(stream, h, p_w1, p_b1, t1, nullptr, M, VV, DD, DD, VV, VV, 1);
  g1(stream, t1, p_w2, p_b2, t2, nullptr, M, VV, VV, VV, VV, VV, 1);
  g1(stream, t2, p_w3, p_b3, (float*)d_out, nullptr, M, VV, VV, VV, VV, VV, 0);
}

// Round 3
// 1285.006 us; speedup vs baseline: 4.1493x; 2.6007x over previous
//
#include <hip/hip_runtime.h>
#include <hip/hip_bf16.h>
#include <stdint.h>

#define BB 2
#define SS 1024
#define VV 513
#define VP 576          // 513 padded to 9*64
#define DD 512
#define HH 8
#define DKK 64
#define DFFN 2048
#define LL 6
#define MM (BB * SS)    // 2048

typedef __bf16 bf16x8 __attribute__((ext_vector_type(8)));
typedef float f32x4 __attribute__((ext_vector_type(4)));
typedef unsigned short us8 __attribute__((ext_vector_type(8)));

static __device__ inline unsigned short f2bf(float f) {
  union { float f; unsigned u; } v; v.f = f;
  unsigned u = v.u;
  unsigned r = (u + 0x7FFFu + ((u >> 16) & 1u)) >> 16;
  return (unsigned short)r;
}

static __device__ inline bf16x8 ldfrag(const unsigned short* p) {
  us8 r = *(const us8*)p;
  return __builtin_bit_cast(bf16x8, r);
}

typedef __attribute__((address_space(3))) void lds_void;
typedef const __attribute__((address_space(1))) void glb_void;
static __device__ inline void gl_lds16(const void* g, void* l) {
  __builtin_amdgcn_global_load_lds((glb_void*)g, (lds_void*)l, 16, 0, 0);
}

// swizzled LDS fragment read: tile is [64 rows][64 k] bf16, linear 128B rows,
// byte ^= (row&7)<<4 swizzle (matches pre-swizzled global source in staging)
static __device__ inline bf16x8 ldfrag_swz(const unsigned short* base, int row, int kloc) {
  const unsigned byte = (unsigned)(row * 128 + kloc * 2) ^ (unsigned)((row & 7) << 4);
  return ldfrag((const unsigned short*)((const char*)base + byte));
}

// ---------------------------------------------------------------------------
// GEMM: C = A[M][Kp](bf16) * B^T  where B is stored [N][Kp] bf16 (padded).
// M=2048, Np,Kp multiples of 64. 64x64x64 tiles, 4 waves, double-buffered
// global_load_lds staging. NB = fused (B,out) pairs sharing A.
// ---------------------------------------------------------------------------
struct GemmP {
  const unsigned short* A;
  const unsigned short* B0; const unsigned short* B1; const unsigned short* B2;
  const float* bias;
  float* C;                                   // optional f32 out (stride ldc, col<Nreal)
  unsigned short* D0; unsigned short* D1; unsigned short* D2;  // bf16 out, stride Np
  int Kp, Np, ldc, Nreal, relu;
};

template<int NB>
__global__ __launch_bounds__(256)
void gemm_tpl(GemmP p)
{
  __shared__ unsigned short Al[2][64 * 64];
  __shared__ unsigned short Bl[2][64 * 64];
  const int tid = threadIdx.x;
  const int l = tid & 63, w = tid >> 6;
  const int wm = w >> 1, wn = w & 1;
  const int lr = l & 15, lg = l >> 4;

  const int nbn = p.Np >> 6;
  int sel = 0, bx = blockIdx.x;
  if (NB > 1) { sel = bx / nbn; bx -= sel * nbn; }
  const unsigned short* Bmat = p.B0;
  if (NB > 1 && sel == 1) Bmat = p.B1;
  if (NB > 2 && sel == 2) Bmat = p.B2;
  const int m0 = blockIdx.y << 6, n0 = bx << 6;

  f32x4 acc[2][2];
  const f32x4 zf = {0.f, 0.f, 0.f, 0.f};
#pragma unroll
  for (int i = 0; i < 2; ++i)
#pragma unroll
    for (int j = 0; j < 2; ++j) acc[i][j] = zf;

  const size_t Kp = (size_t)p.Kp;
  const unsigned short* Abase = p.A + (size_t)m0 * Kp;
  const unsigned short* Bbase = Bmat + (size_t)n0 * Kp;

  // stage one 64x64 bf16 tile pair into buf: 2+2 global_load_lds x16B per thread
  auto stage = [&](int buf, int kt) {
    const int k0 = kt << 6;
#pragma unroll
    for (int j = 0; j < 2; ++j) {
      const int ti = j * 256 + tid;
      const int row = ti >> 3;
      const int sinner = (ti & 7) ^ (row & 7);      // pre-swizzled source chunk
      gl_lds16(Abase + (size_t)row * Kp + k0 + sinner * 8, &Al[buf][ti * 8]);
    }
#pragma unroll
    for (int j = 0; j < 2; ++j) {
      const int ti = j * 256 + tid;
      const int row = ti >> 3;
      const int sinner = (ti & 7) ^ (row & 7);
      gl_lds16(Bbase + (size_t)row * Kp + k0 + sinner * 8, &Bl[buf][ti * 8]);
    }
  };

  const int nt = p.Kp >> 6;
  int cur = 0;
  stage(0, 0);
  asm volatile("s_waitcnt vmcnt(0)" ::: "memory");
  __syncthreads();

  for (int kt = 0; kt < nt; ++kt) {
    if (kt + 1 < nt) stage(cur ^ 1, kt + 1);   // async prefetch overlaps MFMA below
#pragma unroll
    for (int ks = 0; ks < 2; ++ks) {
      bf16x8 af[2], bfv[2];
#pragma unroll
      for (int mf = 0; mf < 2; ++mf)
        af[mf] = ldfrag_swz(Al[cur], wm * 32 + mf * 16 + lr, ks * 32 + lg * 8);
#pragma unroll
      for (int nf = 0; nf < 2; ++nf)
        bfv[nf] = ldfrag_swz(Bl[cur], wn * 32 + nf * 16 + lr, ks * 32 + lg * 8);
#pragma unroll
      for (int mf = 0; mf < 2; ++mf)
#pragma unroll
        for (int nf = 0; nf < 2; ++nf)
          acc[mf][nf] = __builtin_amdgcn_mfma_f32_16x16x32_bf16(af[mf], bfv[nf], acc[mf][nf], 0, 0, 0);
    }
    if (kt + 1 < nt) {
      asm volatile("s_waitcnt vmcnt(0)" ::: "memory");
      __syncthreads();
    }
    cur ^= 1;
  }

  // epilogue
  unsigned short* Dsel = p.D0;
  if (NB > 1 && sel == 1) Dsel = p.D1;
  if (NB > 2 && sel == 2) Dsel = p.D2;
#pragma unroll
  for (int mf = 0; mf < 2; ++mf) {
#pragma unroll
    for (int r = 0; r < 4; ++r) {
      const int grow = m0 + wm * 32 + mf * 16 + (lg << 2) + r;
#pragma unroll
      for (int nf = 0; nf < 2; ++nf) {
        const int gcol = n0 + wn * 32 + nf * 16 + lr;
        float v = acc[mf][nf][r];
        if (p.bias && gcol < p.Nreal) v += p.bias[gcol];
        if (p.relu) v = fmaxf(v, 0.f);
        if (Dsel) Dsel[(size_t)grow * p.Np + gcol] = f2bf(v);
        if (p.C && gcol < p.Nreal) p.C[(size_t)grow * p.ldc + gcol] = v;
      }
    }
  }
}

// ---------------------------------------------------------------------------
// Flash attention, bf16 in/out. O written in-place over Q (each block reads
// only its own Q rows before writing them).
// ---------------------------------------------------------------------------
__global__ __launch_bounds__(256)
void attn_kernel(const unsigned short* __restrict__ Qb,
                 const unsigned short* __restrict__ Kb,
                 const unsigned short* __restrict__ Vb,
                 unsigned short* __restrict__ Ob,
                 const int* __restrict__ keyvalid, int causal)
{
  __shared__ unsigned short Kl[64 * 72];
  __shared__ unsigned short Vt[64 * 72];
  __shared__ unsigned short Pl[4 * 16 * 72];
  const int tid = threadIdx.x;
  const int l = tid & 63, w = tid >> 6;
  const int qt = blockIdx.x, h = blockIdx.y, b = blockIdx.z;
  const int lr = l & 15, lg = l >> 4;
  const int qbase = qt * 64 + w * 16;

  bf16x8 qf[2];
  {
    const unsigned short* qrow = Qb + ((size_t)(b * SS) + qbase + lr) * DD + h * DKK;
    qf[0] = ldfrag(qrow + (lg << 3));
    qf[1] = ldfrag(qrow + 32 + (lg << 3));
  }

  f32x4 accO[4];
  const f32x4 zf = {0.f, 0.f, 0.f, 0.f};
#pragma unroll
  for (int i = 0; i < 4; ++i) accO[i] = zf;
  float mold[4] = {-1e30f, -1e30f, -1e30f, -1e30f};
  float lsum[4] = {0.f, 0.f, 0.f, 0.f};

  const int ktmax = causal ? (qt + 1) : (SS / 64);
  for (int kt = 0; kt < ktmax; ++kt) {
    {
      const int key = tid >> 2;
      const unsigned short* kr = Kb + ((size_t)(b * SS) + kt * 64 + key) * DD + h * DKK;
#pragma unroll
      for (int s2 = 0; s2 < 2; ++s2) {
        const int fg = (tid & 3) * 2 + s2;
        *(us8*)(&Kl[key * 72 + fg * 8]) = *(const us8*)(kr + fg * 8);
      }
    }
    {
      const int d = tid & 63, kg = tid >> 6;
#pragma unroll
      for (int s2 = 0; s2 < 2; ++s2) {
        const int kb = (kg + 4 * s2) << 3;
        us8 t;
#pragma unroll
        for (int j = 0; j < 8; ++j)
          t[j] = Vb[((size_t)(b * SS) + kt * 64 + kb + j) * DD + h * DKK + d];
        *(us8*)(&Vt[d * 72 + kb]) = t;
      }
    }
    __syncthreads();
    float sc[4][4];
#pragma unroll
    for (int nf = 0; nf < 4; ++nf) {
      f32x4 s = zf;
      bf16x8 k0 = ldfrag(&Kl[(nf * 16 + lr) * 72 + (lg << 3)]);
      bf16x8 k1 = ldfrag(&Kl[(nf * 16 + lr) * 72 + 32 + (lg << 3)]);
      s = __builtin_amdgcn_mfma_f32_16x16x32_bf16(qf[0], k0, s, 0, 0, 0);
      s = __builtin_amdgcn_mfma_f32_16x16x32_bf16(qf[1], k1, s, 0, 0, 0);
      const int kglob = kt * 64 + nf * 16 + lr;
      const int kv = keyvalid[b * SS + kglob];
#pragma unroll
      for (int r = 0; r < 4; ++r) {
        const int qglob = qbase + (lg << 2) + r;
        const bool ok = kv && (!causal || kglob <= qglob);
        sc[nf][r] = ok ? s[r] * 0.125f : -1e9f;
      }
    }
#pragma unroll
    for (int r = 0; r < 4; ++r) {
      float mloc = fmaxf(fmaxf(sc[0][r], sc[1][r]), fmaxf(sc[2][r], sc[3][r]));
#pragma unroll
      for (int off = 1; off < 16; off <<= 1)
        mloc = fmaxf(mloc, __shfl_xor(mloc, off, 64));
      const float mnew = fmaxf(mold[r], mloc);
      const float corr = __expf(mold[r] - mnew);
      float ps = 0.f;
#pragma unroll
      for (int nf = 0; nf < 4; ++nf) {
        const float pv = __expf(sc[nf][r] - mnew);
        sc[nf][r] = pv;
        ps += pv;
      }
#pragma unroll
      for (int off = 1; off < 16; off <<= 1)
        ps += __shfl_xor(ps, off, 64);
      lsum[r] = lsum[r] * corr + ps;
#pragma unroll
      for (int nf = 0; nf < 4; ++nf) accO[nf][r] *= corr;
      mold[r] = mnew;
    }
    unsigned short* pw = &Pl[w * 16 * 72];
#pragma unroll
    for (int nf = 0; nf < 4; ++nf)
#pragma unroll
      for (int r = 0; r < 4; ++r)
        pw[((lg << 2) + r) * 72 + nf * 16 + lr] = f2bf(sc[nf][r]);
    __syncthreads();
    bf16x8 pa0 = ldfrag(&pw[lr * 72 + (lg << 3)]);
    bf16x8 pa1 = ldfrag(&pw[lr * 72 + 32 + (lg << 3)]);
#pragma unroll
    for (int nf = 0; nf < 4; ++nf) {
      bf16x8 v0 = ldfrag(&Vt[(nf * 16 + lr) * 72 + (lg << 3)]);
      bf16x8 v1 = ldfrag(&Vt[(nf * 16 + lr) * 72 + 32 + (lg << 3)]);
      accO[nf] = __builtin_amdgcn_mfma_f32_16x16x32_bf16(pa0, v0, accO[nf], 0, 0, 0);
      accO[nf] = __builtin_amdgcn_mfma_f32_16x16x32_bf16(pa1, v1, accO[nf], 0, 0, 0);
    }
    __syncthreads();
  }
#pragma unroll
  for (int r = 0; r < 4; ++r) {
    const float inv = 1.f / lsum[r];
    const size_t orow = ((size_t)(b * SS) + qbase + (lg << 2) + r) * DD + h * DKK;
#pragma unroll
    for (int nf = 0; nf < 4; ++nf)
      Ob[orow + nf * 16 + lr] = f2bf(accO[nf][r] * inv);
  }
}

// ---------------------------------------------------------------------------
// out = LN(a + c); writes f32 residual and bf16 mirror
// ---------------------------------------------------------------------------
__global__ __launch_bounds__(64)
void addln_kernel(const float* __restrict__ a, const float* __restrict__ c,
                  const float* __restrict__ g, const float* __restrict__ bb,
                  float* __restrict__ hf, unsigned short* __restrict__ hb)
{
  const int row = blockIdx.x, l = threadIdx.x;
  const float* ar = a + (size_t)row * DD;
  const float* cr = c + (size_t)row * DD;
  float x[8];
  float sum = 0.f;
#pragma unroll
  for (int j = 0; j < 8; ++j) { x[j] = ar[l + 64 * j] + cr[l + 64 * j]; sum += x[j]; }
#pragma unroll
  for (int off = 1; off < 64; off <<= 1) sum += __shfl_xor(sum, off, 64);
  const float mean = sum * (1.f / 512.f);
  float vs = 0.f;
#pragma unroll
  for (int j = 0; j < 8; ++j) { const float d = x[j] - mean; vs += d * d; }
#pragma unroll
  for (int off = 1; off < 64; off <<= 1) vs += __shfl_xor(vs, off, 64);
  const float rs = rsqrtf(vs * (1.f / 512.f) + 1e-6f);
  float* of = hf + (size_t)row * DD;
  unsigned short* ob = hb + (size_t)row * DD;
#pragma unroll
  for (int j = 0; j < 8; ++j) {
    const int col = l + 64 * j;
    const float v = (x[j] - mean) * rs * g[col] + bb[col];
    of[col] = v;
    ob[col] = f2bf(v);
  }
}

__global__ __launch_bounds__(64)
void rowvalid_kernel(const float* __restrict__ x, int n, int* __restrict__ out)
{
  const int row = blockIdx.x, l = threadIdx.x;
  const float* xr = x + (size_t)row * n;
  int ok = 1;
  for (int j = l; j < n; j += 64) ok &= (xr[j] != -1.0f) ? 1 : 0;
  ok = __all(ok) ? 1 : 0;
  if (l == 0) out[row] = ok;
}

// transposed sinusoid table: tabT[d][s] bf16, d<512, s<1024
__global__ void postable_kernel(unsigned short* __restrict__ tabT)
{
  const int i = blockIdx.x * blockDim.x + threadIdx.x;
  if (i >= DD * SS) return;
  const int d = i >> 10, s = i & 1023;
  const float ex = (float)(2 * (d >> 1)) * (1.0f / (float)DD);
  const float ang = (float)s * powf(10000.0f, -ex);
  tabT[i] = f2bf((d & 1) ? cosf(ang) : sinf(ang));
}

// weighted kernel combine -> bf16 [2048][1024]
__global__ void gpec_kernel(const float* __restrict__ gk, unsigned short* __restrict__ Mb)
{
  const int i = blockIdx.x * blockDim.x + threadIdx.x;
  if (i >= BB * SS * SS) return;
  const int b = i / (SS * SS);
  const int rem = i - b * (SS * SS);
  const float* p = gk + (size_t)b * 3 * SS * SS + rem;
  Mb[i] = f2bf((p[0] + 0.9f * p[SS * SS] + 0.81f * p[2 * SS * SS]) * (1.0f / 2.71f));
}

// W [L][K][N] f32 -> WT [L][Np][Kp] bf16, zero-padded. grid (Np/64, Kp/64, L)
__global__ __launch_bounds__(256)
void wconv_kernel(const float* __restrict__ W, unsigned short* __restrict__ WT,
                  int K, int N, int Kp, int Np)
{
  __shared__ float t[64][65];
  const float* Wl = W + (size_t)blockIdx.z * K * N;
  unsigned short* WTl = WT + (size_t)blockIdx.z * Np * Kp;
  const int n0 = blockIdx.x << 6, k0 = blockIdx.y << 6;
  const int tid = threadIdx.x;
  const int cx = tid & 63, ry = tid >> 6;
#pragma unroll
  for (int i = 0; i < 16; ++i) {
    const int kk = k0 + ry + i * 4, nn = n0 + cx;
    t[ry + i * 4][cx] = (kk < K && nn < N) ? Wl[(size_t)kk * N + nn] : 0.f;
  }
  __syncthreads();
#pragma unroll
  for (int i = 0; i < 16; ++i) {
    const int nn = n0 + ry + i * 4, kk = k0 + cx;
    WTl[(size_t)nn * Kp + kk] = f2bf(t[cx][ry + i * 4]);
  }
}

// f32 [rows][N] -> bf16 [rows][Np] zero-padded
__global__ void aconv_kernel(const float* __restrict__ A, unsigned short* __restrict__ Ab,
                             int N, int Np, int total)
{
  const int i = blockIdx.x * blockDim.x + threadIdx.x;
  if (i >= total) return;
  const int row = i / Np, col = i - row * Np;
  Ab[i] = (col < N) ? f2bf(A[(size_t)row * N + col]) : (unsigned short)0;
}

// ---------------------------------------------------------------------------
static inline void g1(hipStream_t s, const unsigned short* A, const unsigned short* B,
                      const float* bias, float* C, unsigned short* D,
                      int Kp, int Np, int ldc, int Nreal, int relu)
{
  GemmP p{};
  p.A = A; p.B0 = B; p.bias = bias; p.C = C; p.D0 = D;
  p.Kp = Kp; p.Np = Np; p.ldc = ldc; p.Nreal = Nreal; p.relu = relu;
  gemm_tpl<1><<<dim3(Np >> 6, MM >> 6), 256, 0, s>>>(p);
}

static inline void g2(hipStream_t s, const unsigned short* A, const unsigned short* B0,
                      const unsigned short* B1, unsigned short* D0, unsigned short* D1,
                      int Kp, int Np)
{
  GemmP p{};
  p.A = A; p.B0 = B0; p.B1 = B1; p.D0 = D0; p.D1 = D1;
  p.Kp = Kp; p.Np = Np; p.ldc = Np; p.Nreal = Np; p.relu = 0;
  gemm_tpl<2><<<dim3(2 * (Np >> 6), MM >> 6), 256, 0, s>>>(p);
}

static inline void g3(hipStream_t s, const unsigned short* A, const unsigned short* B0,
                      const unsigned short* B1, const unsigned short* B2,
                      unsigned short* D0, unsigned short* D1, unsigned short* D2,
                      int Kp, int Np)
{
  GemmP p{};
  p.A = A; p.B0 = B0; p.B1 = B1; p.B2 = B2; p.D0 = D0; p.D1 = D1; p.D2 = D2;
  p.Kp = Kp; p.Np = Np; p.ldc = Np; p.Nreal = Np; p.relu = 0;
  gemm_tpl<3><<<dim3(3 * (Np >> 6), MM >> 6), 256, 0, s>>>(p);
}

extern "C" void kernel_launch(void* const* d_in, const int* in_sizes, int n_in,
                              void* d_out, int out_size, void* d_ws, size_t ws_size,
                              hipStream_t stream)
{
  (void)in_sizes; (void)n_in; (void)out_size; (void)ws_size;
  const float* dec_in = (const float*)d_in[0];
  const float* prev   = (const float*)d_in[1];
  const float* gk     = (const float*)d_in[6];
  const float* emb_w1 = (const float*)d_in[7];
  const float* emb_b1 = (const float*)d_in[8];
  const float* emb_w2 = (const float*)d_in[9];
  const float* emb_b2 = (const float*)d_in[10];
  const float* emb_w3 = (const float*)d_in[11];
  const float* emb_b3 = (const float*)d_in[12];
  const float* ln0_g  = (const float*)d_in[13];
  const float* ln0_b  = (const float*)d_in[14];
  const float* wq     = (const float*)d_in[15];
  const float* wk     = (const float*)d_in[16];
  const float* wv     = (const float*)d_in[17];
  const float* wo     = (const float*)d_in[18];
  const float* cq     = (const float*)d_in[19];
  const float* ck     = (const float*)d_in[20];
  const float* cv     = (const float*)d_in[21];
  const float* co     = (const float*)d_in[22];
  const float* ffn_w1 = (const float*)d_in[23];
  const float* ffn_w2 = (const float*)d_in[24];
  const float* ffn_b1 = (const float*)d_in[25];
  const float* ffn_b2 = (const float*)d_in[26];
  const float* ln1_g  = (const float*)d_in[27];
  const float* ln1_b  = (const float*)d_in[28];
  const float* ln2_g  = (const float*)d_in[29];
  const float* ln2_b  = (const float*)d_in[30];
  const float* ln3_g  = (const float*)d_in[31];
  const float* ln3_b  = (const float*)d_in[32];
  const float* p_w1   = (const float*)d_in[33];
  const float* p_b1   = (const float*)d_in[34];
  const float* p_w2   = (const float*)d_in[35];
  const float* p_b2   = (const float*)d_in[36];
  const float* p_w3   = (const float*)d_in[37];
  const float* p_b3   = (const float*)d_in[38];

  // ---- workspace carve (256B aligned) ----
  char* wsp = (char*)d_ws;
  auto carve = [&](size_t bytes) { char* r = wsp; wsp += (bytes + 255) & ~(size_t)255; return r; };

  unsigned short* decb  = (unsigned short*)carve((size_t)MM * VP * 2);
  unsigned short* prevb = (unsigned short*)carve((size_t)MM * DD * 2);
  float*          hf    = (float*)carve((size_t)MM * DD * 4);
  unsigned short* hb    = (unsigned short*)carve((size_t)MM * DD * 2);
  float*          xf1   = (float*)carve((size_t)MM * DD * 4);
  unsigned short* tb1   = (unsigned short*)carve((size_t)MM * DFFN * 2);   // 8 MB
  unsigned short* Mbb   = tb1;                                   // alias: first 4 MB
  float*          xf2   = (float*)((char*)tb1 + (size_t)MM * SS * 2);      // alias: last 4 MB
  unsigned short* tb2a  = (unsigned short*)carve((size_t)MM * VP * 2);
  unsigned short* tb2b  = (unsigned short*)carve((size_t)MM * VP * 2);
  unsigned short* qb    = (unsigned short*)carve((size_t)MM * DD * 2);
  unsigned short* kb    = (unsigned short*)carve((size_t)MM * DD * 2);
  unsigned short* vb    = (unsigned short*)carve((size_t)MM * DD * 2);
  int* kvs = (int*)carve((size_t)MM * 4);
  int* kve = (int*)carve((size_t)MM * 4);
  unsigned short* postabt = (unsigned short*)carve((size_t)DD * SS * 2);
  unsigned short* ew1t  = (unsigned short*)carve((size_t)VP * VP * 2);
  unsigned short* ew2t  = (unsigned short*)carve((size_t)VP * VP * 2);
  unsigned short* ew3t  = (unsigned short*)carve((size_t)DD * VP * 2);
  unsigned short* wqt   = (unsigned short*)carve((size_t)LL * DD * DD * 2);
  unsigned short* wkt   = (unsigned short*)carve((size_t)LL * DD * DD * 2);
  unsigned short* wvt   = (unsigned short*)carve((size_t)LL * DD * DD * 2);
  unsigned short* wot   = (unsigned short*)carve((size_t)LL * DD * DD * 2);
  unsigned short* cqt   = (unsigned short*)carve((size_t)LL * DD * DD * 2);
  unsigned short* ckt   = (unsigned short*)carve((size_t)LL * DD * DD * 2);
  unsigned short* cvt   = (unsigned short*)carve((size_t)LL * DD * DD * 2);
  unsigned short* cot   = (unsigned short*)carve((size_t)LL * DD * DD * 2);
  unsigned short* f1t   = (unsigned short*)carve((size_t)LL * DFFN * DD * 2);
  unsigned short* f2t   = (unsigned short*)carve((size_t)LL * DD * DFFN * 2);
  unsigned short* p1t   = (unsigned short*)carve((size_t)VP * DD * 2);
  unsigned short* p2t   = (unsigned short*)carve((size_t)VP * VP * 2);
  unsigned short* p3t   = (unsigned short*)carve((size_t)VP * VP * 2);

  // ---- prep: conversions / tables / masks ----
  rowvalid_kernel<<<MM, 64, 0, stream>>>(dec_in, VV, kvs);
  rowvalid_kernel<<<MM, 64, 0, stream>>>(prev, DD, kve);
  aconv_kernel<<<(MM * VP + 255) / 256, 256, 0, stream>>>(dec_in, decb, VV, VP, MM * VP);
  aconv_kernel<<<(MM * DD + 255) / 256, 256, 0, stream>>>(prev, prevb, DD, DD, MM * DD);
  postable_kernel<<<(DD * SS + 255) / 256, 256, 0, stream>>>(postabt);
  gpec_kernel<<<(BB * SS * SS + 255) / 256, 256, 0, stream>>>(gk, Mbb);

  wconv_kernel<<<dim3(9, 9, 1), 256, 0, stream>>>(emb_w1, ew1t, VV, VV, VP, VP);
  wconv_kernel<<<dim3(9, 9, 1), 256, 0, stream>>>(emb_w2, ew2t, VV, VV, VP, VP);
  wconv_kernel<<<dim3(8, 9, 1), 256, 0, stream>>>(emb_w3, ew3t, VV, DD, VP, DD);
  wconv_kernel<<<dim3(8, 8, LL), 256, 0, stream>>>(wq, wqt, DD, DD, DD, DD);
  wconv_kernel<<<dim3(8, 8, LL), 256, 0, stream>>>(wk, wkt, DD, DD, DD, DD);
  wconv_kernel<<<dim3(8, 8, LL), 256, 0, stream>>>(wv, wvt, DD, DD, DD, DD);
  wconv_kernel<<<dim3(8, 8, LL), 256, 0, stream>>>(wo, wot, DD, DD, DD, DD);
  wconv_kernel<<<dim3(8, 8, LL), 256, 0, stream>>>(cq, cqt, DD, DD, DD, DD);
  wconv_kernel<<<dim3(8, 8, LL), 256, 0, stream>>>(ck, ckt, DD, DD, DD, DD);
  wconv_kernel<<<dim3(8, 8, LL), 256, 0, stream>>>(cv, cvt, DD, DD, DD, DD);
  wconv_kernel<<<dim3(8, 8, LL), 256, 0, stream>>>(co, cot, DD, DD, DD, DD);
  wconv_kernel<<<dim3(32, 8, LL), 256, 0, stream>>>(ffn_w1, f1t, DD, DFFN, DD, DFFN);
  wconv_kernel<<<dim3(8, 32, LL), 256, 0, stream>>>(ffn_w2, f2t, DFFN, DD, DFFN, DD);
  wconv_kernel<<<dim3(9, 8, 1), 256, 0, stream>>>(p_w1, p1t, DD, VV, DD, VP);
  wconv_kernel<<<dim3(9, 9, 1), 256, 0, stream>>>(p_w2, p2t, VV, VV, VP, VP);
  wconv_kernel<<<dim3(9, 9, 1), 256, 0, stream>>>(p_w3, p3t, VV, VV, VP, VP);

  // ---- embedding MLP + graph positional encoding ----
  g1(stream, decb, ew1t, emb_b1, nullptr, tb2a, VP, VP, VP, VV, 1);
  g1(stream, tb2a, ew2t, emb_b2, nullptr, tb2b, VP, VP, VP, VV, 1);
  g1(stream, tb2b, ew3t, emb_b3, xf1, nullptr, VP, DD, DD, DD, 0);
  g1(stream, Mbb, postabt, nullptr, xf2, nullptr, SS, DD, DD, DD, 0);
  addln_kernel<<<MM, 64, 0, stream>>>(xf1, xf2, ln0_g, ln0_b, hf, hb);

  for (int i = 0; i < LL; ++i) {
    const size_t od = (size_t)i * DD * DD;
    // self attention
    g3(stream, hb, wqt + od, wkt + od, wvt + od, qb, kb, vb, DD, DD);
    attn_kernel<<<dim3(SS / 64, HH, BB), 256, 0, stream>>>(qb, kb, vb, qb, kvs, 1);
    g1(stream, qb, wot + od, nullptr, xf1, nullptr, DD, DD, DD, DD, 0);
    addln_kernel<<<MM, 64, 0, stream>>>(hf, xf1, ln1_g + i * DD, ln1_b + i * DD, hf, hb);
    // cross attention
    g1(stream, hb, cqt + od, nullptr, nullptr, qb, DD, DD, DD, DD, 0);
    g2(stream, prevb, ckt + od, cvt + od, kb, vb, DD, DD);
    attn_kernel<<<dim3(SS / 64, HH, BB), 256, 0, stream>>>(qb, kb, vb, qb, kve, 0);
    g1(stream, qb, cot + od, nullptr, xf1, nullptr, DD, DD, DD, DD, 0);
    addln_kernel<<<MM, 64, 0, stream>>>(hf, xf1, ln2_g + i * DD, ln2_b + i * DD, hf, hb);
    // FFN
    g1(stream, hb, f1t + (size_t)i * DFFN * DD, ffn_b1 + i * DFFN, nullptr, tb1, DD, DFFN, DFFN, DFFN, 1);
    g1(stream, tb1, f2t + (size_t)i * DD * DFFN, ffn_b2 + i * DD, xf1, nullptr, DFFN, DD, DD, DD, 0);
    addln_kernel<<<MM, 64, 0, stream>>>(hf, xf1, ln3_g + i * DD, ln3_b + i * DD, hf, hb);
  }

  // ---- output head ----
  g1(stream, hb, p1t, p_b1, nullptr, tb2a, DD, VP, VP, VV, 1);
  g1(stream, tb2a, p2t, p_b2, nullptr, tb2b, VP, VP, VP, VV, 1);
  g1(stream, tb2b, p3t, p_b3, (float*)d_out, nullptr, VP, VP, VV, VV, 0);
}

// Round 4
// 1207.310 us; speedup vs baseline: 4.4163x; 1.0644x over previous
//
#include <hip/hip_runtime.h>
#include <hip/hip_bf16.h>
#include <stdint.h>

#define BB 2
#define SS 1024
#define VV 513
#define VP 576          // 513 padded to 9*64
#define DD 512
#define HH 8
#define DKK 64
#define DFFN 2048
#define LL 6
#define MM (BB * SS)    // 2048

typedef __bf16 bf16x8 __attribute__((ext_vector_type(8)));
typedef float f32x4 __attribute__((ext_vector_type(4)));
typedef unsigned short us8 __attribute__((ext_vector_type(8)));

static __device__ inline unsigned short f2bf(float f) {
  union { float f; unsigned u; } v; v.f = f;
  unsigned u = v.u;
  unsigned r = (u + 0x7FFFu + ((u >> 16) & 1u)) >> 16;
  return (unsigned short)r;
}

static __device__ inline bf16x8 ldfrag(const unsigned short* p) {
  us8 r = *(const us8*)p;
  return __builtin_bit_cast(bf16x8, r);
}

typedef __attribute__((address_space(3))) void lds_void;
typedef const __attribute__((address_space(1))) void glb_void;
static __device__ inline void gl_lds16(const void* g, void* l) {
  __builtin_amdgcn_global_load_lds((glb_void*)g, (lds_void*)l, 16, 0, 0);
}

// swizzled LDS fragment read: tile is [64 rows][64 k] bf16, linear 128B rows,
// byte ^= (row&7)<<4 swizzle (matches pre-swizzled global source in staging)
static __device__ inline bf16x8 ldfrag_swz(const unsigned short* base, int row, int kloc) {
  const unsigned byte = (unsigned)(row * 128 + kloc * 2) ^ (unsigned)((row & 7) << 4);
  return ldfrag((const unsigned short*)((const char*)base + byte));
}

// ---------------------------------------------------------------------------
// GEMM: C = A[M][Kp](bf16) * B^T  where B is stored [N][Kp] bf16 (padded).
// ---------------------------------------------------------------------------
struct GemmP {
  const unsigned short* A;
  const unsigned short* B0; const unsigned short* B1; const unsigned short* B2;
  const float* bias;
  float* C;
  unsigned short* D0; unsigned short* D1; unsigned short* D2;
  int Kp, Np, ldc, Nreal, relu;
};

template<int NB>
__global__ __launch_bounds__(256)
void gemm_tpl(GemmP p)
{
  __shared__ unsigned short Al[2][64 * 64];
  __shared__ unsigned short Bl[2][64 * 64];
  const int tid = threadIdx.x;
  const int l = tid & 63, w = tid >> 6;
  const int wm = w >> 1, wn = w & 1;
  const int lr = l & 15, lg = l >> 4;

  const int nbn = p.Np >> 6;
  int sel = 0, bx = blockIdx.x;
  if (NB > 1) { sel = bx / nbn; bx -= sel * nbn; }
  const unsigned short* Bmat = p.B0;
  if (NB > 1 && sel == 1) Bmat = p.B1;
  if (NB > 2 && sel == 2) Bmat = p.B2;
  const int m0 = blockIdx.y << 6, n0 = bx << 6;

  f32x4 acc[2][2];
  const f32x4 zf = {0.f, 0.f, 0.f, 0.f};
#pragma unroll
  for (int i = 0; i < 2; ++i)
#pragma unroll
    for (int j = 0; j < 2; ++j) acc[i][j] = zf;

  const size_t Kp = (size_t)p.Kp;
  const unsigned short* Abase = p.A + (size_t)m0 * Kp;
  const unsigned short* Bbase = Bmat + (size_t)n0 * Kp;

  auto stage = [&](int buf, int kt) {
    const int k0 = kt << 6;
#pragma unroll
    for (int j = 0; j < 2; ++j) {
      const int ti = j * 256 + tid;
      const int row = ti >> 3;
      const int sinner = (ti & 7) ^ (row & 7);
      gl_lds16(Abase + (size_t)row * Kp + k0 + sinner * 8, &Al[buf][ti * 8]);
    }
#pragma unroll
    for (int j = 0; j < 2; ++j) {
      const int ti = j * 256 + tid;
      const int row = ti >> 3;
      const int sinner = (ti & 7) ^ (row & 7);
      gl_lds16(Bbase + (size_t)row * Kp + k0 + sinner * 8, &Bl[buf][ti * 8]);
    }
  };

  const int nt = p.Kp >> 6;
  int cur = 0;
  stage(0, 0);
  asm volatile("s_waitcnt vmcnt(0)" ::: "memory");
  __syncthreads();

  for (int kt = 0; kt < nt; ++kt) {
    if (kt + 1 < nt) stage(cur ^ 1, kt + 1);
#pragma unroll
    for (int ks = 0; ks < 2; ++ks) {
      bf16x8 af[2], bfv[2];
#pragma unroll
      for (int mf = 0; mf < 2; ++mf)
        af[mf] = ldfrag_swz(Al[cur], wm * 32 + mf * 16 + lr, ks * 32 + lg * 8);
#pragma unroll
      for (int nf = 0; nf < 2; ++nf)
        bfv[nf] = ldfrag_swz(Bl[cur], wn * 32 + nf * 16 + lr, ks * 32 + lg * 8);
#pragma unroll
      for (int mf = 0; mf < 2; ++mf)
#pragma unroll
        for (int nf = 0; nf < 2; ++nf)
          acc[mf][nf] = __builtin_amdgcn_mfma_f32_16x16x32_bf16(af[mf], bfv[nf], acc[mf][nf], 0, 0, 0);
    }
    if (kt + 1 < nt) {
      asm volatile("s_waitcnt vmcnt(0)" ::: "memory");
      __syncthreads();
    }
    cur ^= 1;
  }

  unsigned short* Dsel = p.D0;
  if (NB > 1 && sel == 1) Dsel = p.D1;
  if (NB > 2 && sel == 2) Dsel = p.D2;
#pragma unroll
  for (int mf = 0; mf < 2; ++mf) {
#pragma unroll
    for (int r = 0; r < 4; ++r) {
      const int grow = m0 + wm * 32 + mf * 16 + (lg << 2) + r;
#pragma unroll
      for (int nf = 0; nf < 2; ++nf) {
        const int gcol = n0 + wn * 32 + nf * 16 + lr;
        float v = acc[mf][nf][r];
        if (p.bias && gcol < p.Nreal) v += p.bias[gcol];
        if (p.relu) v = fmaxf(v, 0.f);
        if (Dsel) Dsel[(size_t)grow * p.Np + gcol] = f2bf(v);
        if (p.C && gcol < p.Nreal) p.C[(size_t)grow * p.ldc + gcol] = v;
      }
    }
  }
}

// ---------------------------------------------------------------------------
// V transpose: vb [B*S][512] bf16 -> vbT [B][H][64][1024] bf16
// ---------------------------------------------------------------------------
__global__ __launch_bounds__(256)
void vtrans_kernel(const unsigned short* __restrict__ vb, unsigned short* __restrict__ vbT)
{
  __shared__ unsigned short t[64][72];
  const int s0 = blockIdx.x << 6, h = blockIdx.y, b = blockIdx.z;
  const int tid = threadIdx.x;
  const int rr = tid >> 2, cbase = (tid & 3) * 2;
#pragma unroll
  for (int j = 0; j < 2; ++j) {
    const int ch = cbase + j;
    *(us8*)&t[rr][ch * 8] = *(const us8*)(vb + ((size_t)(b * SS) + s0 + rr) * DD + h * DKK + ch * 8);
  }
  __syncthreads();
#pragma unroll
  for (int j = 0; j < 2; ++j) {
    const int ch = cbase + j;
    us8 o;
#pragma unroll
    for (int e = 0; e < 8; ++e) o[e] = t[ch * 8 + e][rr];
    *(us8*)(vbT + (((size_t)(b * HH) + h) * DKK + rr) * SS + s0 + ch * 8) = o;
  }
}

// ---------------------------------------------------------------------------
// Flash attention, double-buffered async staging. V pre-transposed.
// O written in-place over Q (each block reads only its own Q rows).
// ---------------------------------------------------------------------------
template<int CAUSAL>
__global__ __launch_bounds__(256)
void attn_kernel(const unsigned short* __restrict__ Qb,
                 const unsigned short* __restrict__ Kb,
                 const unsigned short* __restrict__ VbT,
                 unsigned short* __restrict__ Ob,
                 const float* __restrict__ maskadd)
{
  __shared__ unsigned short Kl[2][64 * 64];
  __shared__ unsigned short Vl[2][64 * 64];
  __shared__ unsigned short Pl[4 * 16 * 72];
  const int tid = threadIdx.x;
  const int l = tid & 63, w = tid >> 6;
  const int qt = blockIdx.x, h = blockIdx.y, b = blockIdx.z;
  const int lr = l & 15, lg = l >> 4;
  const int qbase = qt * 64 + w * 16;

  bf16x8 qf[2];
  {
    const unsigned short* qrow = Qb + ((size_t)(b * SS) + qbase + lr) * DD + h * DKK;
    qf[0] = ldfrag(qrow + (lg << 3));
    qf[1] = ldfrag(qrow + 32 + (lg << 3));
  }

  const unsigned short* Kbase = Kb + (size_t)(b * SS) * DD + h * DKK;
  const unsigned short* Vbase = VbT + ((size_t)(b * HH) + h) * DKK * SS;

  auto stage = [&](int buf, int kt) {
#pragma unroll
    for (int j = 0; j < 2; ++j) {
      const int ti = j * 256 + tid;
      const int row = ti >> 3;
      const int ch = (ti & 7) ^ (row & 7);
      gl_lds16(Kbase + (size_t)(kt * 64 + row) * DD + ch * 8, &Kl[buf][ti * 8]);
    }
#pragma unroll
    for (int j = 0; j < 2; ++j) {
      const int ti = j * 256 + tid;
      const int row = ti >> 3;
      const int ch = (ti & 7) ^ (row & 7);
      gl_lds16(Vbase + (size_t)row * SS + kt * 64 + ch * 8, &Vl[buf][ti * 8]);
    }
  };

  f32x4 accO[4];
  const f32x4 zf = {0.f, 0.f, 0.f, 0.f};
#pragma unroll
  for (int i = 0; i < 4; ++i) accO[i] = zf;
  float mold[4] = {-1e30f, -1e30f, -1e30f, -1e30f};
  float lsum[4] = {0.f, 0.f, 0.f, 0.f};

  const int ktmax = CAUSAL ? (qt + 1) : (SS / 64);
  stage(0, 0);
  asm volatile("s_waitcnt vmcnt(0)" ::: "memory");
  __syncthreads();

  for (int kt = 0; kt < ktmax; ++kt) {
    const int cur = kt & 1;
    if (kt + 1 < ktmax) stage(cur ^ 1, kt + 1);
    // QK^T
    float sc[4][4];
#pragma unroll
    for (int nf = 0; nf < 4; ++nf) {
      f32x4 s = zf;
      bf16x8 k0 = ldfrag_swz(Kl[cur], nf * 16 + lr, lg * 8);
      bf16x8 k1 = ldfrag_swz(Kl[cur], nf * 16 + lr, 32 + lg * 8);
      s = __builtin_amdgcn_mfma_f32_16x16x32_bf16(qf[0], k0, s, 0, 0, 0);
      s = __builtin_amdgcn_mfma_f32_16x16x32_bf16(qf[1], k1, s, 0, 0, 0);
      const int kglob = kt * 64 + nf * 16 + lr;
      const float madd = maskadd[b * SS + kglob];
#pragma unroll
      for (int r = 0; r < 4; ++r) {
        const int qglob = qbase + (lg << 2) + r;
        sc[nf][r] = (CAUSAL && kglob > qglob) ? -1e9f : s[r] * 0.125f + madd;
      }
    }
    // online softmax (rows live in 16-lane groups)
#pragma unroll
    for (int r = 0; r < 4; ++r) {
      float mloc = fmaxf(fmaxf(sc[0][r], sc[1][r]), fmaxf(sc[2][r], sc[3][r]));
#pragma unroll
      for (int off = 1; off < 16; off <<= 1)
        mloc = fmaxf(mloc, __shfl_xor(mloc, off, 64));
      const float mnew = fmaxf(mold[r], mloc);
      const float corr = __expf(mold[r] - mnew);
      float ps = 0.f;
#pragma unroll
      for (int nf = 0; nf < 4; ++nf) {
        const float pv = __expf(sc[nf][r] - mnew);
        sc[nf][r] = pv;
        ps += pv;
      }
#pragma unroll
      for (int off = 1; off < 16; off <<= 1)
        ps += __shfl_xor(ps, off, 64);
      lsum[r] = lsum[r] * corr + ps;
#pragma unroll
      for (int nf = 0; nf < 4; ++nf) accO[nf][r] *= corr;
      mold[r] = mnew;
    }
    // P transpose via per-wave LDS region (in-wave ordering only)
    unsigned short* pw = &Pl[w * 16 * 72];
#pragma unroll
    for (int nf = 0; nf < 4; ++nf)
#pragma unroll
      for (int r = 0; r < 4; ++r)
        pw[((lg << 2) + r) * 72 + nf * 16 + lr] = f2bf(sc[nf][r]);
    bf16x8 pa0 = ldfrag(&pw[lr * 72 + (lg << 3)]);
    bf16x8 pa1 = ldfrag(&pw[lr * 72 + 32 + (lg << 3)]);
    // PV: B-operand rows are d (V^T rows)
#pragma unroll
    for (int nf = 0; nf < 4; ++nf) {
      bf16x8 v0 = ldfrag_swz(Vl[cur], nf * 16 + lr, lg * 8);
      bf16x8 v1 = ldfrag_swz(Vl[cur], nf * 16 + lr, 32 + lg * 8);
      accO[nf] = __builtin_amdgcn_mfma_f32_16x16x32_bf16(pa0, v0, accO[nf], 0, 0, 0);
      accO[nf] = __builtin_amdgcn_mfma_f32_16x16x32_bf16(pa1, v1, accO[nf], 0, 0, 0);
    }
    asm volatile("s_waitcnt vmcnt(0)" ::: "memory");
    __syncthreads();
  }
#pragma unroll
  for (int r = 0; r < 4; ++r) {
    const float inv = 1.f / lsum[r];
    const size_t orow = ((size_t)(b * SS) + qbase + (lg << 2) + r) * DD + h * DKK;
#pragma unroll
    for (int nf = 0; nf < 4; ++nf)
      Ob[orow + nf * 16 + lr] = f2bf(accO[nf][r] * inv);
  }
}

// ---------------------------------------------------------------------------
// out = LN(a + c); 4 rows per block, vectorized
// ---------------------------------------------------------------------------
__global__ __launch_bounds__(256)
void addln_kernel(const float* __restrict__ a, const float* __restrict__ c,
                  const float* __restrict__ g, const float* __restrict__ bb,
                  float* __restrict__ hf, unsigned short* __restrict__ hb)
{
  const int row = blockIdx.x * 4 + (threadIdx.x >> 6);
  const int l = threadIdx.x & 63;
  const float* ar = a + (size_t)row * DD + l * 8;
  const float* cr = c + (size_t)row * DD + l * 8;
  f32x4 x0 = *(const f32x4*)ar + *(const f32x4*)cr;
  f32x4 x1 = *(const f32x4*)(ar + 4) + *(const f32x4*)(cr + 4);
  float sum = x0[0] + x0[1] + x0[2] + x0[3] + x1[0] + x1[1] + x1[2] + x1[3];
#pragma unroll
  for (int off = 1; off < 64; off <<= 1) sum += __shfl_xor(sum, off, 64);
  const float mean = sum * (1.f / 512.f);
  float vs = 0.f;
#pragma unroll
  for (int j = 0; j < 4; ++j) { float d0 = x0[j] - mean; float d1 = x1[j] - mean; vs += d0 * d0 + d1 * d1; }
#pragma unroll
  for (int off = 1; off < 64; off <<= 1) vs += __shfl_xor(vs, off, 64);
  const float rs = rsqrtf(vs * (1.f / 512.f) + 1e-6f);
  const f32x4 g0 = *(const f32x4*)(g + l * 8), g1 = *(const f32x4*)(g + l * 8 + 4);
  const f32x4 b0 = *(const f32x4*)(bb + l * 8), b1 = *(const f32x4*)(bb + l * 8 + 4);
  f32x4 o0, o1;
  us8 ob;
#pragma unroll
  for (int j = 0; j < 4; ++j) {
    o0[j] = (x0[j] - mean) * rs * g0[j] + b0[j];
    o1[j] = (x1[j] - mean) * rs * g1[j] + b1[j];
    ob[j] = f2bf(o0[j]); ob[j + 4] = f2bf(o1[j]);
  }
  float* of = hf + (size_t)row * DD + l * 8;
  *(f32x4*)of = o0; *(f32x4*)(of + 4) = o1;
  *(us8*)(hb + (size_t)row * DD + l * 8) = ob;
}

// row-valid -> additive mask (0 or -1e9)
__global__ __launch_bounds__(64)
void rowvalid_kernel(const float* __restrict__ x, int n, float* __restrict__ out)
{
  const int row = blockIdx.x, l = threadIdx.x;
  const float* xr = x + (size_t)row * n;
  int ok = 1;
  for (int j = l; j < n; j += 64) ok &= (xr[j] != -1.0f) ? 1 : 0;
  ok = __all(ok) ? 1 : 0;
  if (l == 0) out[row] = ok ? 0.f : -1e9f;
}

// transposed sinusoid table: tabT[d][s] bf16
__global__ void postable_kernel(unsigned short* __restrict__ tabT)
{
  const int i = blockIdx.x * blockDim.x + threadIdx.x;
  if (i >= DD * SS) return;
  const int d = i >> 10, s = i & 1023;
  const float ex = (float)(2 * (d >> 1)) * (1.0f / (float)DD);
  const float ang = (float)s * powf(10000.0f, -ex);
  tabT[i] = f2bf((d & 1) ? cosf(ang) : sinf(ang));
}

__global__ void gpec_kernel(const float* __restrict__ gk, unsigned short* __restrict__ Mb)
{
  const int i = blockIdx.x * blockDim.x + threadIdx.x;
  if (i >= BB * SS * SS) return;
  const int b = i / (SS * SS);
  const int rem = i - b * (SS * SS);
  const float* p = gk + (size_t)b * 3 * SS * SS + rem;
  Mb[i] = f2bf((p[0] + 0.9f * p[SS * SS] + 0.81f * p[2 * SS * SS]) * (1.0f / 2.71f));
}

// W [L][K][N] f32 -> WT [L][Np][Kp] bf16, zero-padded
__global__ __launch_bounds__(256)
void wconv_kernel(const float* __restrict__ W, unsigned short* __restrict__ WT,
                  int K, int N, int Kp, int Np)
{
  __shared__ float t[64][65];
  const float* Wl = W + (size_t)blockIdx.z * K * N;
  unsigned short* WTl = WT + (size_t)blockIdx.z * Np * Kp;
  const int n0 = blockIdx.x << 6, k0 = blockIdx.y << 6;
  const int tid = threadIdx.x;
  const int cx = tid & 63, ry = tid >> 6;
#pragma unroll
  for (int i = 0; i < 16; ++i) {
    const int kk = k0 + ry + i * 4, nn = n0 + cx;
    t[ry + i * 4][cx] = (kk < K && nn < N) ? Wl[(size_t)kk * N + nn] : 0.f;
  }
  __syncthreads();
#pragma unroll
  for (int i = 0; i < 16; ++i) {
    const int nn = n0 + ry + i * 4, kk = k0 + cx;
    WTl[(size_t)nn * Kp + kk] = f2bf(t[cx][ry + i * 4]);
  }
}

__global__ void aconv_kernel(const float* __restrict__ A, unsigned short* __restrict__ Ab,
                             int N, int Np, int total)
{
  const int i = blockIdx.x * blockDim.x + threadIdx.x;
  if (i >= total) return;
  const int row = i / Np, col = i - row * Np;
  Ab[i] = (col < N) ? f2bf(A[(size_t)row * N + col]) : (unsigned short)0;
}

// ---------------------------------------------------------------------------
static inline void g1(hipStream_t s, const unsigned short* A, const unsigned short* B,
                      const float* bias, float* C, unsigned short* D,
                      int Kp, int Np, int ldc, int Nreal, int relu)
{
  GemmP p{};
  p.A = A; p.B0 = B; p.bias = bias; p.C = C; p.D0 = D;
  p.Kp = Kp; p.Np = Np; p.ldc = ldc; p.Nreal = Nreal; p.relu = relu;
  gemm_tpl<1><<<dim3(Np >> 6, MM >> 6), 256, 0, s>>>(p);
}

static inline void g2(hipStream_t s, const unsigned short* A, const unsigned short* B0,
                      const unsigned short* B1, unsigned short* D0, unsigned short* D1,
                      int Kp, int Np)
{
  GemmP p{};
  p.A = A; p.B0 = B0; p.B1 = B1; p.D0 = D0; p.D1 = D1;
  p.Kp = Kp; p.Np = Np; p.ldc = Np; p.Nreal = Np; p.relu = 0;
  gemm_tpl<2><<<dim3(2 * (Np >> 6), MM >> 6), 256, 0, s>>>(p);
}

static inline void g3(hipStream_t s, const unsigned short* A, const unsigned short* B0,
                      const unsigned short* B1, const unsigned short* B2,
                      unsigned short* D0, unsigned short* D1, unsigned short* D2,
                      int Kp, int Np)
{
  GemmP p{};
  p.A = A; p.B0 = B0; p.B1 = B1; p.B2 = B2; p.D0 = D0; p.D1 = D1; p.D2 = D2;
  p.Kp = Kp; p.Np = Np; p.ldc = Np; p.Nreal = Np; p.relu = 0;
  gemm_tpl<3><<<dim3(3 * (Np >> 6), MM >> 6), 256, 0, s>>>(p);
}

extern "C" void kernel_launch(void* const* d_in, const int* in_sizes, int n_in,
                              void* d_out, int out_size, void* d_ws, size_t ws_size,
                              hipStream_t stream)
{
  (void)in_sizes; (void)n_in; (void)out_size; (void)ws_size;
  const float* dec_in = (const float*)d_in[0];
  const float* prev   = (const float*)d_in[1];
  const float* gk     = (const float*)d_in[6];
  const float* emb_w1 = (const float*)d_in[7];
  const float* emb_b1 = (const float*)d_in[8];
  const float* emb_w2 = (const float*)d_in[9];
  const float* emb_b2 = (const float*)d_in[10];
  const float* emb_w3 = (const float*)d_in[11];
  const float* emb_b3 = (const float*)d_in[12];
  const float* ln0_g  = (const float*)d_in[13];
  const float* ln0_b  = (const float*)d_in[14];
  const float* wq     = (const float*)d_in[15];
  const float* wk     = (const float*)d_in[16];
  const float* wv     = (const float*)d_in[17];
  const float* wo     = (const float*)d_in[18];
  const float* cq     = (const float*)d_in[19];
  const float* ck     = (const float*)d_in[20];
  const float* cv     = (const float*)d_in[21];
  const float* co     = (const float*)d_in[22];
  const float* ffn_w1 = (const float*)d_in[23];
  const float* ffn_w2 = (const float*)d_in[24];
  const float* ffn_b1 = (const float*)d_in[25];
  const float* ffn_b2 = (const float*)d_in[26];
  const float* ln1_g  = (const float*)d_in[27];
  const float* ln1_b  = (const float*)d_in[28];
  const float* ln2_g  = (const float*)d_in[29];
  const float* ln2_b  = (const float*)d_in[30];
  const float* ln3_g  = (const float*)d_in[31];
  const float* ln3_b  = (const float*)d_in[32];
  const float* p_w1   = (const float*)d_in[33];
  const float* p_b1   = (const float*)d_in[34];
  const float* p_w2   = (const float*)d_in[35];
  const float* p_b2   = (const float*)d_in[36];
  const float* p_w3   = (const float*)d_in[37];
  const float* p_b3   = (const float*)d_in[38];

  // ---- workspace carve ----
  char* wsp = (char*)d_ws;
  auto carve = [&](size_t bytes) { char* r = wsp; wsp += (bytes + 255) & ~(size_t)255; return r; };

  unsigned short* decb  = (unsigned short*)carve((size_t)MM * VP * 2);
  unsigned short* prevb = (unsigned short*)carve((size_t)MM * DD * 2);
  float*          hf    = (float*)carve((size_t)MM * DD * 4);
  unsigned short* hb    = (unsigned short*)carve((size_t)MM * DD * 2);
  float*          xf1   = (float*)carve((size_t)MM * DD * 4);
  unsigned short* tb1   = (unsigned short*)carve((size_t)MM * DFFN * 2);   // 8 MB
  unsigned short* Mbb   = tb1;                                   // alias: first 4 MB
  float*          xf2   = (float*)((char*)tb1 + (size_t)MM * SS * 2);      // alias: last 4 MB
  unsigned short* tb2a  = (unsigned short*)carve((size_t)MM * VP * 2);
  unsigned short* tb2b  = (unsigned short*)carve((size_t)MM * VP * 2);
  unsigned short* qb    = (unsigned short*)carve((size_t)MM * DD * 2);
  unsigned short* kb    = (unsigned short*)carve((size_t)MM * DD * 2);
  unsigned short* vb    = (unsigned short*)carve((size_t)MM * DD * 2);
  unsigned short* vbT   = (unsigned short*)carve((size_t)MM * DD * 2);
  float* kvs = (float*)carve((size_t)MM * 4);
  float* kve = (float*)carve((size_t)MM * 4);
  unsigned short* postabt = (unsigned short*)carve((size_t)DD * SS * 2);
  unsigned short* ew1t  = (unsigned short*)carve((size_t)VP * VP * 2);
  unsigned short* ew2t  = (unsigned short*)carve((size_t)VP * VP * 2);
  unsigned short* ew3t  = (unsigned short*)carve((size_t)DD * VP * 2);
  unsigned short* wqt   = (unsigned short*)carve((size_t)LL * DD * DD * 2);
  unsigned short* wkt   = (unsigned short*)carve((size_t)LL * DD * DD * 2);
  unsigned short* wvt   = (unsigned short*)carve((size_t)LL * DD * DD * 2);
  unsigned short* wot   = (unsigned short*)carve((size_t)LL * DD * DD * 2);
  unsigned short* cqt   = (unsigned short*)carve((size_t)LL * DD * DD * 2);
  unsigned short* ckt   = (unsigned short*)carve((size_t)LL * DD * DD * 2);
  unsigned short* cvt   = (unsigned short*)carve((size_t)LL * DD * DD * 2);
  unsigned short* cot   = (unsigned short*)carve((size_t)LL * DD * DD * 2);
  unsigned short* f1t   = (unsigned short*)carve((size_t)LL * DFFN * DD * 2);
  unsigned short* f2t   = (unsigned short*)carve((size_t)LL * DD * DFFN * 2);
  unsigned short* p1t   = (unsigned short*)carve((size_t)VP * DD * 2);
  unsigned short* p2t   = (unsigned short*)carve((size_t)VP * VP * 2);
  unsigned short* p3t   = (unsigned short*)carve((size_t)VP * VP * 2);

  // ---- prep ----
  rowvalid_kernel<<<MM, 64, 0, stream>>>(dec_in, VV, kvs);
  rowvalid_kernel<<<MM, 64, 0, stream>>>(prev, DD, kve);
  aconv_kernel<<<(MM * VP + 255) / 256, 256, 0, stream>>>(dec_in, decb, VV, VP, MM * VP);
  aconv_kernel<<<(MM * DD + 255) / 256, 256, 0, stream>>>(prev, prevb, DD, DD, MM * DD);
  postable_kernel<<<(DD * SS + 255) / 256, 256, 0, stream>>>(postabt);
  gpec_kernel<<<(BB * SS * SS + 255) / 256, 256, 0, stream>>>(gk, Mbb);

  wconv_kernel<<<dim3(9, 9, 1), 256, 0, stream>>>(emb_w1, ew1t, VV, VV, VP, VP);
  wconv_kernel<<<dim3(9, 9, 1), 256, 0, stream>>>(emb_w2, ew2t, VV, VV, VP, VP);
  wconv_kernel<<<dim3(8, 9, 1), 256, 0, stream>>>(emb_w3, ew3t, VV, DD, VP, DD);
  wconv_kernel<<<dim3(8, 8, LL), 256, 0, stream>>>(wq, wqt, DD, DD, DD, DD);
  wconv_kernel<<<dim3(8, 8, LL), 256, 0, stream>>>(wk, wkt, DD, DD, DD, DD);
  wconv_kernel<<<dim3(8, 8, LL), 256, 0, stream>>>(wv, wvt, DD, DD, DD, DD);
  wconv_kernel<<<dim3(8, 8, LL), 256, 0, stream>>>(wo, wot, DD, DD, DD, DD);
  wconv_kernel<<<dim3(8, 8, LL), 256, 0, stream>>>(cq, cqt, DD, DD, DD, DD);
  wconv_kernel<<<dim3(8, 8, LL), 256, 0, stream>>>(ck, ckt, DD, DD, DD, DD);
  wconv_kernel<<<dim3(8, 8, LL), 256, 0, stream>>>(cv, cvt, DD, DD, DD, DD);
  wconv_kernel<<<dim3(8, 8, LL), 256, 0, stream>>>(co, cot, DD, DD, DD, DD);
  wconv_kernel<<<dim3(32, 8, LL), 256, 0, stream>>>(ffn_w1, f1t, DD, DFFN, DD, DFFN);
  wconv_kernel<<<dim3(8, 32, LL), 256, 0, stream>>>(ffn_w2, f2t, DFFN, DD, DFFN, DD);
  wconv_kernel<<<dim3(9, 8, 1), 256, 0, stream>>>(p_w1, p1t, DD, VV, DD, VP);
  wconv_kernel<<<dim3(9, 9, 1), 256, 0, stream>>>(p_w2, p2t, VV, VV, VP, VP);
  wconv_kernel<<<dim3(9, 9, 1), 256, 0, stream>>>(p_w3, p3t, VV, VV, VP, VP);

  // ---- embedding MLP + graph positional encoding ----
  g1(stream, decb, ew1t, emb_b1, nullptr, tb2a, VP, VP, VP, VV, 1);
  g1(stream, tb2a, ew2t, emb_b2, nullptr, tb2b, VP, VP, VP, VV, 1);
  g1(stream, tb2b, ew3t, emb_b3, xf1, nullptr, VP, DD, DD, DD, 0);
  g1(stream, Mbb, postabt, nullptr, xf2, nullptr, SS, DD, DD, DD, 0);
  addln_kernel<<<MM / 4, 256, 0, stream>>>(xf1, xf2, ln0_g, ln0_b, hf, hb);

  const dim3 agrid(SS / 64, HH, BB);
  const dim3 vgrid(SS / 64, HH, BB);
  for (int i = 0; i < LL; ++i) {
    const size_t od = (size_t)i * DD * DD;
    // self attention
    g3(stream, hb, wqt + od, wkt + od, wvt + od, qb, kb, vb, DD, DD);
    vtrans_kernel<<<vgrid, 256, 0, stream>>>(vb, vbT);
    attn_kernel<1><<<agrid, 256, 0, stream>>>(qb, kb, vbT, qb, kvs);
    g1(stream, qb, wot + od, nullptr, xf1, nullptr, DD, DD, DD, DD, 0);
    addln_kernel<<<MM / 4, 256, 0, stream>>>(hf, xf1, ln1_g + i * DD, ln1_b + i * DD, hf, hb);
    // cross attention
    g1(stream, hb, cqt + od, nullptr, nullptr, qb, DD, DD, DD, DD, 0);
    g2(stream, prevb, ckt + od, cvt + od, kb, vb, DD, DD);
    vtrans_kernel<<<vgrid, 256, 0, stream>>>(vb, vbT);
    attn_kernel<0><<<agrid, 256, 0, stream>>>(qb, kb, vbT, qb, kve);
    g1(stream, qb, cot + od, nullptr, xf1, nullptr, DD, DD, DD, DD, 0);
    addln_kernel<<<MM / 4, 256, 0, stream>>>(hf, xf1, ln2_g + i * DD, ln2_b + i * DD, hf, hb);
    // FFN
    g1(stream, hb, f1t + (size_t)i * DFFN * DD, ffn_b1 + i * DFFN, nullptr, tb1, DD, DFFN, DFFN, DFFN, 1);
    g1(stream, tb1, f2t + (size_t)i * DD * DFFN, ffn_b2 + i * DD, xf1, nullptr, DFFN, DD, DD, DD, 0);
    addln_kernel<<<MM / 4, 256, 0, stream>>>(hf, xf1, ln3_g + i * DD, ln3_b + i * DD, hf, hb);
  }

  // ---- output head ----
  g1(stream, hb, p1t, p_b1, nullptr, tb2a, DD, VP, VP, VV, 1);
  g1(stream, tb2a, p2t, p_b2, nullptr, tb2b, VP, VP, VP, VV, 1);
  g1(stream, tb2b, p3t, p_b3, (float*)d_out, nullptr, VP, VP, VV, VV, 0);
}

// Round 5
// 1169.023 us; speedup vs baseline: 4.5610x; 1.0328x over previous
//
#include <hip/hip_runtime.h>
#include <hip/hip_bf16.h>
#include <stdint.h>

#define BB 2
#define SS 1024
#define VV 513
#define VP 576          // 513 padded to 9*64
#define DD 512
#define HH 8
#define DKK 64
#define DFFN 2048
#define LL 6
#define MM (BB * SS)    // 2048

typedef __bf16 bf16x8 __attribute__((ext_vector_type(8)));
typedef float f32x4 __attribute__((ext_vector_type(4)));
typedef unsigned short us8 __attribute__((ext_vector_type(8)));

static __device__ inline unsigned short f2bf(float f) {
  union { float f; unsigned u; } v; v.f = f;
  unsigned u = v.u;
  unsigned r = (u + 0x7FFFu + ((u >> 16) & 1u)) >> 16;
  return (unsigned short)r;
}

static __device__ inline bf16x8 ldfrag(const unsigned short* p) {
  us8 r = *(const us8*)p;
  return __builtin_bit_cast(bf16x8, r);
}

typedef __attribute__((address_space(3))) void lds_void;
typedef const __attribute__((address_space(1))) void glb_void;
static __device__ inline void gl_lds16(const void* g, void* l) {
  __builtin_amdgcn_global_load_lds((glb_void*)g, (lds_void*)l, 16, 0, 0);
}

// swizzled LDS fragment read: tile is [64 rows][64 k] bf16, linear 128B rows,
// byte ^= (row&7)<<4 swizzle (matches pre-swizzled global source in staging)
static __device__ inline bf16x8 ldfrag_swz(const unsigned short* base, int row, int kloc) {
  const unsigned byte = (unsigned)(row * 128 + kloc * 2) ^ (unsigned)((row & 7) << 4);
  return ldfrag((const unsigned short*)((const char*)base + byte));
}

// ---------------------------------------------------------------------------
// GEMM: C = A[M][Kp](bf16) * B^T  where B is stored [N][Kp] bf16 (padded).
// ---------------------------------------------------------------------------
struct GemmP {
  const unsigned short* A;
  const unsigned short* B0; const unsigned short* B1; const unsigned short* B2;
  const float* bias;
  float* C;
  unsigned short* D0; unsigned short* D1; unsigned short* D2;
  int Kp, Np, ldc, Nreal, relu;
};

template<int NB>
__global__ __launch_bounds__(256)
void gemm_tpl(GemmP p)
{
  __shared__ unsigned short Al[2][64 * 64];
  __shared__ unsigned short Bl[2][64 * 64];
  const int tid = threadIdx.x;
  const int l = tid & 63, w = tid >> 6;
  const int wm = w >> 1, wn = w & 1;
  const int lr = l & 15, lg = l >> 4;

  const int nbn = p.Np >> 6;
  int sel = 0, bx = blockIdx.x;
  if (NB > 1) { sel = bx / nbn; bx -= sel * nbn; }
  const unsigned short* Bmat = p.B0;
  if (NB > 1 && sel == 1) Bmat = p.B1;
  if (NB > 2 && sel == 2) Bmat = p.B2;
  const int m0 = blockIdx.y << 6, n0 = bx << 6;

  f32x4 acc[2][2];
  const f32x4 zf = {0.f, 0.f, 0.f, 0.f};
#pragma unroll
  for (int i = 0; i < 2; ++i)
#pragma unroll
    for (int j = 0; j < 2; ++j) acc[i][j] = zf;

  const size_t Kp = (size_t)p.Kp;
  const unsigned short* Abase = p.A + (size_t)m0 * Kp;
  const unsigned short* Bbase = Bmat + (size_t)n0 * Kp;

  auto stage = [&](int buf, int kt) {
    const int k0 = kt << 6;
#pragma unroll
    for (int j = 0; j < 2; ++j) {
      const int ti = j * 256 + tid;
      const int row = ti >> 3;
      const int sinner = (ti & 7) ^ (row & 7);
      gl_lds16(Abase + (size_t)row * Kp + k0 + sinner * 8, &Al[buf][ti * 8]);
    }
#pragma unroll
    for (int j = 0; j < 2; ++j) {
      const int ti = j * 256 + tid;
      const int row = ti >> 3;
      const int sinner = (ti & 7) ^ (row & 7);
      gl_lds16(Bbase + (size_t)row * Kp + k0 + sinner * 8, &Bl[buf][ti * 8]);
    }
  };

  const int nt = p.Kp >> 6;
  int cur = 0;
  stage(0, 0);
  asm volatile("s_waitcnt vmcnt(0)" ::: "memory");
  __syncthreads();

  for (int kt = 0; kt < nt; ++kt) {
    if (kt + 1 < nt) stage(cur ^ 1, kt + 1);
#pragma unroll
    for (int ks = 0; ks < 2; ++ks) {
      bf16x8 af[2], bfv[2];
#pragma unroll
      for (int mf = 0; mf < 2; ++mf)
        af[mf] = ldfrag_swz(Al[cur], wm * 32 + mf * 16 + lr, ks * 32 + lg * 8);
#pragma unroll
      for (int nf = 0; nf < 2; ++nf)
        bfv[nf] = ldfrag_swz(Bl[cur], wn * 32 + nf * 16 + lr, ks * 32 + lg * 8);
#pragma unroll
      for (int mf = 0; mf < 2; ++mf)
#pragma unroll
        for (int nf = 0; nf < 2; ++nf)
          acc[mf][nf] = __builtin_amdgcn_mfma_f32_16x16x32_bf16(af[mf], bfv[nf], acc[mf][nf], 0, 0, 0);
    }
    if (kt + 1 < nt) {
      asm volatile("s_waitcnt vmcnt(0)" ::: "memory");
      __syncthreads();
    }
    cur ^= 1;
  }

  unsigned short* Dsel = p.D0;
  if (NB > 1 && sel == 1) Dsel = p.D1;
  if (NB > 2 && sel == 2) Dsel = p.D2;
#pragma unroll
  for (int mf = 0; mf < 2; ++mf) {
#pragma unroll
    for (int r = 0; r < 4; ++r) {
      const int grow = m0 + wm * 32 + mf * 16 + (lg << 2) + r;
#pragma unroll
      for (int nf = 0; nf < 2; ++nf) {
        const int gcol = n0 + wn * 32 + nf * 16 + lr;
        float v = acc[mf][nf][r];
        if (p.bias && gcol < p.Nreal) v += p.bias[gcol];
        if (p.relu) v = fmaxf(v, 0.f);
        if (Dsel) Dsel[(size_t)grow * p.Np + gcol] = f2bf(v);
        if (p.C && gcol < p.Nreal) p.C[(size_t)grow * p.ldc + gcol] = v;
      }
    }
  }
}

// ---------------------------------------------------------------------------
// Batched GEMM over 12 (B,D) pairs sharing A. Np=Kp=512, bf16 out only.
// ---------------------------------------------------------------------------
struct GemmBat {
  const unsigned short* A;
  const unsigned short* B[12];
  unsigned short* D[12];
  int Kp, Np;
};

__global__ __launch_bounds__(256)
void gemm_bat(GemmBat p)
{
  __shared__ unsigned short Al[2][64 * 64];
  __shared__ unsigned short Bl[2][64 * 64];
  const int tid = threadIdx.x;
  const int l = tid & 63, w = tid >> 6;
  const int wm = w >> 1, wn = w & 1;
  const int lr = l & 15, lg = l >> 4;

  const int nbn = p.Np >> 6;
  const int sel = blockIdx.x / nbn;
  const int bx = blockIdx.x - sel * nbn;
  const unsigned short* Bmat = p.B[sel];
  unsigned short* Dmat = p.D[sel];
  const int m0 = blockIdx.y << 6, n0 = bx << 6;

  f32x4 acc[2][2];
  const f32x4 zf = {0.f, 0.f, 0.f, 0.f};
#pragma unroll
  for (int i = 0; i < 2; ++i)
#pragma unroll
    for (int j = 0; j < 2; ++j) acc[i][j] = zf;

  const size_t Kp = (size_t)p.Kp;
  const unsigned short* Abase = p.A + (size_t)m0 * Kp;
  const unsigned short* Bbase = Bmat + (size_t)n0 * Kp;

  auto stage = [&](int buf, int kt) {
    const int k0 = kt << 6;
#pragma unroll
    for (int j = 0; j < 2; ++j) {
      const int ti = j * 256 + tid;
      const int row = ti >> 3;
      const int sinner = (ti & 7) ^ (row & 7);
      gl_lds16(Abase + (size_t)row * Kp + k0 + sinner * 8, &Al[buf][ti * 8]);
    }
#pragma unroll
    for (int j = 0; j < 2; ++j) {
      const int ti = j * 256 + tid;
      const int row = ti >> 3;
      const int sinner = (ti & 7) ^ (row & 7);
      gl_lds16(Bbase + (size_t)row * Kp + k0 + sinner * 8, &Bl[buf][ti * 8]);
    }
  };

  const int nt = p.Kp >> 6;
  int cur = 0;
  stage(0, 0);
  asm volatile("s_waitcnt vmcnt(0)" ::: "memory");
  __syncthreads();

  for (int kt = 0; kt < nt; ++kt) {
    if (kt + 1 < nt) stage(cur ^ 1, kt + 1);
#pragma unroll
    for (int ks = 0; ks < 2; ++ks) {
      bf16x8 af[2], bfv[2];
#pragma unroll
      for (int mf = 0; mf < 2; ++mf)
        af[mf] = ldfrag_swz(Al[cur], wm * 32 + mf * 16 + lr, ks * 32 + lg * 8);
#pragma unroll
      for (int nf = 0; nf < 2; ++nf)
        bfv[nf] = ldfrag_swz(Bl[cur], wn * 32 + nf * 16 + lr, ks * 32 + lg * 8);
#pragma unroll
      for (int mf = 0; mf < 2; ++mf)
#pragma unroll
        for (int nf = 0; nf < 2; ++nf)
          acc[mf][nf] = __builtin_amdgcn_mfma_f32_16x16x32_bf16(af[mf], bfv[nf], acc[mf][nf], 0, 0, 0);
    }
    if (kt + 1 < nt) {
      asm volatile("s_waitcnt vmcnt(0)" ::: "memory");
      __syncthreads();
    }
    cur ^= 1;
  }

#pragma unroll
  for (int mf = 0; mf < 2; ++mf) {
#pragma unroll
    for (int r = 0; r < 4; ++r) {
      const int grow = m0 + wm * 32 + mf * 16 + (lg << 2) + r;
#pragma unroll
      for (int nf = 0; nf < 2; ++nf) {
        const int gcol = n0 + wn * 32 + nf * 16 + lr;
        Dmat[(size_t)grow * p.Np + gcol] = f2bf(acc[mf][nf][r]);
      }
    }
  }
}

// ---------------------------------------------------------------------------
// V transpose: src + li*MM*DD, [B*S][512] bf16 -> dst + li*MM*DD as
// [B][H][64][1024] bf16.  blockIdx.z = b + 2*li.
// ---------------------------------------------------------------------------
__global__ __launch_bounds__(256)
void vtrans_kernel(const unsigned short* __restrict__ src, unsigned short* __restrict__ dst)
{
  __shared__ unsigned short t[64][72];
  const int s0 = blockIdx.x << 6, h = blockIdx.y;
  const int b = blockIdx.z & 1, li = blockIdx.z >> 1;
  const unsigned short* vb = src + (size_t)li * MM * DD;
  unsigned short* vbT = dst + (size_t)li * MM * DD;
  const int tid = threadIdx.x;
  const int rr = tid >> 2, cbase = (tid & 3) * 2;
#pragma unroll
  for (int j = 0; j < 2; ++j) {
    const int ch = cbase + j;
    *(us8*)&t[rr][ch * 8] = *(const us8*)(vb + ((size_t)(b * SS) + s0 + rr) * DD + h * DKK + ch * 8);
  }
  __syncthreads();
#pragma unroll
  for (int j = 0; j < 2; ++j) {
    const int ch = cbase + j;
    us8 o;
#pragma unroll
    for (int e = 0; e < 8; ++e) o[e] = t[ch * 8 + e][rr];
    *(us8*)(vbT + (((size_t)(b * HH) + h) * DKK + rr) * SS + s0 + ch * 8) = o;
  }
}

// ---------------------------------------------------------------------------
// Flash attention: QBLK=32, 2 waves/block, double-buffered async staging.
// V pre-transposed. O written in-place over Q.
// ---------------------------------------------------------------------------
template<int CAUSAL>
__global__ __launch_bounds__(128)
void attn_kernel(const unsigned short* __restrict__ Qb,
                 const unsigned short* __restrict__ Kb,
                 const unsigned short* __restrict__ VbT,
                 unsigned short* __restrict__ Ob,
                 const float* __restrict__ maskadd)
{
  __shared__ unsigned short Kl[2][64 * 64];
  __shared__ unsigned short Vl[2][64 * 64];
  __shared__ unsigned short Pl[2 * 16 * 72];
  const int tid = threadIdx.x;
  const int l = tid & 63, w = tid >> 6;
  const int qt = blockIdx.x, h = blockIdx.y, b = blockIdx.z;
  const int lr = l & 15, lg = l >> 4;
  const int qbase = qt * 32 + w * 16;

  bf16x8 qf[2];
  {
    const unsigned short* qrow = Qb + ((size_t)(b * SS) + qbase + lr) * DD + h * DKK;
    qf[0] = ldfrag(qrow + (lg << 3));
    qf[1] = ldfrag(qrow + 32 + (lg << 3));
  }

  const unsigned short* Kbase = Kb + (size_t)(b * SS) * DD + h * DKK;
  const unsigned short* Vbase = VbT + ((size_t)(b * HH) + h) * DKK * SS;

  auto stage = [&](int buf, int kt) {
#pragma unroll
    for (int j = 0; j < 4; ++j) {
      const int ti = j * 128 + tid;
      const int row = ti >> 3;
      const int ch = (ti & 7) ^ (row & 7);
      gl_lds16(Kbase + (size_t)(kt * 64 + row) * DD + ch * 8, &Kl[buf][ti * 8]);
    }
#pragma unroll
    for (int j = 0; j < 4; ++j) {
      const int ti = j * 128 + tid;
      const int row = ti >> 3;
      const int ch = (ti & 7) ^ (row & 7);
      gl_lds16(Vbase + (size_t)row * SS + kt * 64 + ch * 8, &Vl[buf][ti * 8]);
    }
  };

  f32x4 accO[4];
  const f32x4 zf = {0.f, 0.f, 0.f, 0.f};
#pragma unroll
  for (int i = 0; i < 4; ++i) accO[i] = zf;
  float mold[4] = {-1e30f, -1e30f, -1e30f, -1e30f};
  float lsum[4] = {0.f, 0.f, 0.f, 0.f};

  const int ktmax = CAUSAL ? ((qt >> 1) + 1) : (SS / 64);
  stage(0, 0);
  asm volatile("s_waitcnt vmcnt(0)" ::: "memory");
  __syncthreads();

  for (int kt = 0; kt < ktmax; ++kt) {
    const int cur = kt & 1;
    if (kt + 1 < ktmax) stage(cur ^ 1, kt + 1);
    // QK^T
    float sc[4][4];
    __builtin_amdgcn_s_setprio(1);
#pragma unroll
    for (int nf = 0; nf < 4; ++nf) {
      f32x4 s = zf;
      bf16x8 k0 = ldfrag_swz(Kl[cur], nf * 16 + lr, lg * 8);
      bf16x8 k1 = ldfrag_swz(Kl[cur], nf * 16 + lr, 32 + lg * 8);
      s = __builtin_amdgcn_mfma_f32_16x16x32_bf16(qf[0], k0, s, 0, 0, 0);
      s = __builtin_amdgcn_mfma_f32_16x16x32_bf16(qf[1], k1, s, 0, 0, 0);
      const int kglob = kt * 64 + nf * 16 + lr;
      const float madd = maskadd[b * SS + kglob];
#pragma unroll
      for (int r = 0; r < 4; ++r) {
        const int qglob = qbase + (lg << 2) + r;
        sc[nf][r] = (CAUSAL && kglob > qglob) ? -1e9f : s[r] * 0.125f + madd;
      }
    }
    __builtin_amdgcn_s_setprio(0);
    // online softmax (rows live in 16-lane groups)
#pragma unroll
    for (int r = 0; r < 4; ++r) {
      float mloc = fmaxf(fmaxf(sc[0][r], sc[1][r]), fmaxf(sc[2][r], sc[3][r]));
#pragma unroll
      for (int off = 1; off < 16; off <<= 1)
        mloc = fmaxf(mloc, __shfl_xor(mloc, off, 64));
      const float mnew = fmaxf(mold[r], mloc);
      const float corr = __expf(mold[r] - mnew);
      float ps = 0.f;
#pragma unroll
      for (int nf = 0; nf < 4; ++nf) {
        const float pv = __expf(sc[nf][r] - mnew);
        sc[nf][r] = pv;
        ps += pv;
      }
#pragma unroll
      for (int off = 1; off < 16; off <<= 1)
        ps += __shfl_xor(ps, off, 64);
      lsum[r] = lsum[r] * corr + ps;
#pragma unroll
      for (int nf = 0; nf < 4; ++nf) accO[nf][r] *= corr;
      mold[r] = mnew;
    }
    // P transpose via per-wave LDS region (in-wave ordering only)
    unsigned short* pw = &Pl[w * 16 * 72];
#pragma unroll
    for (int nf = 0; nf < 4; ++nf)
#pragma unroll
      for (int r = 0; r < 4; ++r)
        pw[((lg << 2) + r) * 72 + nf * 16 + lr] = f2bf(sc[nf][r]);
    bf16x8 pa0 = ldfrag(&pw[lr * 72 + (lg << 3)]);
    bf16x8 pa1 = ldfrag(&pw[lr * 72 + 32 + (lg << 3)]);
    // PV: B-operand rows are d (V^T rows)
    __builtin_amdgcn_s_setprio(1);
#pragma unroll
    for (int nf = 0; nf < 4; ++nf) {
      bf16x8 v0 = ldfrag_swz(Vl[cur], nf * 16 + lr, lg * 8);
      bf16x8 v1 = ldfrag_swz(Vl[cur], nf * 16 + lr, 32 + lg * 8);
      accO[nf] = __builtin_amdgcn_mfma_f32_16x16x32_bf16(pa0, v0, accO[nf], 0, 0, 0);
      accO[nf] = __builtin_amdgcn_mfma_f32_16x16x32_bf16(pa1, v1, accO[nf], 0, 0, 0);
    }
    __builtin_amdgcn_s_setprio(0);
    asm volatile("s_waitcnt vmcnt(0)" ::: "memory");
    __syncthreads();
  }
#pragma unroll
  for (int r = 0; r < 4; ++r) {
    const float inv = 1.f / lsum[r];
    const size_t orow = ((size_t)(b * SS) + qbase + (lg << 2) + r) * DD + h * DKK;
#pragma unroll
    for (int nf = 0; nf < 4; ++nf)
      Ob[orow + nf * 16 + lr] = f2bf(accO[nf][r] * inv);
  }
}

// ---------------------------------------------------------------------------
// out = LN(a + c); 4 rows per block, vectorized
// ---------------------------------------------------------------------------
__global__ __launch_bounds__(256)
void addln_kernel(const float* __restrict__ a, const float* __restrict__ c,
                  const float* __restrict__ g, const float* __restrict__ bb,
                  float* __restrict__ hf, unsigned short* __restrict__ hb)
{
  const int row = blockIdx.x * 4 + (threadIdx.x >> 6);
  const int l = threadIdx.x & 63;
  const float* ar = a + (size_t)row * DD + l * 8;
  const float* cr = c + (size_t)row * DD + l * 8;
  f32x4 x0 = *(const f32x4*)ar + *(const f32x4*)cr;
  f32x4 x1 = *(const f32x4*)(ar + 4) + *(const f32x4*)(cr + 4);
  float sum = x0[0] + x0[1] + x0[2] + x0[3] + x1[0] + x1[1] + x1[2] + x1[3];
#pragma unroll
  for (int off = 1; off < 64; off <<= 1) sum += __shfl_xor(sum, off, 64);
  const float mean = sum * (1.f / 512.f);
  float vs = 0.f;
#pragma unroll
  for (int j = 0; j < 4; ++j) { float d0 = x0[j] - mean; float d1 = x1[j] - mean; vs += d0 * d0 + d1 * d1; }
#pragma unroll
  for (int off = 1; off < 64; off <<= 1) vs += __shfl_xor(vs, off, 64);
  const float rs = rsqrtf(vs * (1.f / 512.f) + 1e-6f);
  const f32x4 g0 = *(const f32x4*)(g + l * 8), g1 = *(const f32x4*)(g + l * 8 + 4);
  const f32x4 b0 = *(const f32x4*)(bb + l * 8), b1 = *(const f32x4*)(bb + l * 8 + 4);
  f32x4 o0, o1;
  us8 ob;
#pragma unroll
  for (int j = 0; j < 4; ++j) {
    o0[j] = (x0[j] - mean) * rs * g0[j] + b0[j];
    o1[j] = (x1[j] - mean) * rs * g1[j] + b1[j];
    ob[j] = f2bf(o0[j]); ob[j + 4] = f2bf(o1[j]);
  }
  float* of = hf + (size_t)row * DD + l * 8;
  *(f32x4*)of = o0; *(f32x4*)(of + 4) = o1;
  *(us8*)(hb + (size_t)row * DD + l * 8) = ob;
}

// row-valid -> additive mask (0 or -1e9)
__global__ __launch_bounds__(64)
void rowvalid_kernel(const float* __restrict__ x, int n, float* __restrict__ out)
{
  const int row = blockIdx.x, l = threadIdx.x;
  const float* xr = x + (size_t)row * n;
  int ok = 1;
  for (int j = l; j < n; j += 64) ok &= (xr[j] != -1.0f) ? 1 : 0;
  ok = __all(ok) ? 1 : 0;
  if (l == 0) out[row] = ok ? 0.f : -1e9f;
}

// transposed sinusoid table: tabT[d][s] bf16
__global__ void postable_kernel(unsigned short* __restrict__ tabT)
{
  const int i = blockIdx.x * blockDim.x + threadIdx.x;
  if (i >= DD * SS) return;
  const int d = i >> 10, s = i & 1023;
  const float ex = (float)(2 * (d >> 1)) * (1.0f / (float)DD);
  const float ang = (float)s * powf(10000.0f, -ex);
  tabT[i] = f2bf((d & 1) ? cosf(ang) : sinf(ang));
}

__global__ void gpec_kernel(const float* __restrict__ gk, unsigned short* __restrict__ Mb)
{
  const int i = blockIdx.x * blockDim.x + threadIdx.x;
  if (i >= BB * SS * SS) return;
  const int b = i / (SS * SS);
  const int rem = i - b * (SS * SS);
  const float* p = gk + (size_t)b * 3 * SS * SS + rem;
  Mb[i] = f2bf((p[0] + 0.9f * p[SS * SS] + 0.81f * p[2 * SS * SS]) * (1.0f / 2.71f));
}

// W [L][K][N] f32 -> WT [L][Np][Kp] bf16, zero-padded (generic, guarded)
__global__ __launch_bounds__(256)
void wconv_kernel(const float* __restrict__ W, unsigned short* __restrict__ WT,
                  int K, int N, int Kp, int Np)
{
  __shared__ float t[64][65];
  const float* Wl = W + (size_t)blockIdx.z * K * N;
  unsigned short* WTl = WT + (size_t)blockIdx.z * Np * Kp;
  const int n0 = blockIdx.x << 6, k0 = blockIdx.y << 6;
  const int tid = threadIdx.x;
  const int cx = tid & 63, ry = tid >> 6;
#pragma unroll
  for (int i = 0; i < 16; ++i) {
    const int kk = k0 + ry + i * 4, nn = n0 + cx;
    t[ry + i * 4][cx] = (kk < K && nn < N) ? Wl[(size_t)kk * N + nn] : 0.f;
  }
  __syncthreads();
#pragma unroll
  for (int i = 0; i < 16; ++i) {
    const int nn = n0 + ry + i * 4, kk = k0 + cx;
    WTl[(size_t)nn * Kp + kk] = f2bf(t[cx][ry + i * 4]);
  }
}

// 8 attention weight sets [L][512][512] in one launch; z = wi*LL + li
struct WconvB { const float* W[8]; unsigned short* WT[8]; };
__global__ __launch_bounds__(256)
void wconv8_kernel(WconvB p)
{
  __shared__ float t[64][65];
  const int z = blockIdx.z;
  const int wi = z / LL, li = z - wi * LL;
  const float* Wl = p.W[wi] + (size_t)li * DD * DD;
  unsigned short* WTl = p.WT[wi] + (size_t)li * DD * DD;
  const int n0 = blockIdx.x << 6, k0 = blockIdx.y << 6;
  const int cx = threadIdx.x & 63, ry = threadIdx.x >> 6;
#pragma unroll
  for (int i = 0; i < 16; ++i)
    t[ry + i * 4][cx] = Wl[(size_t)(k0 + ry + i * 4) * DD + n0 + cx];
  __syncthreads();
#pragma unroll
  for (int i = 0; i < 16; ++i)
    WTl[(size_t)(n0 + ry + i * 4) * DD + k0 + cx] = f2bf(t[cx][ry + i * 4]);
}

__global__ void aconv_kernel(const float* __restrict__ A, unsigned short* __restrict__ Ab,
                             int N, int Np, int total)
{
  const int i = blockIdx.x * blockDim.x + threadIdx.x;
  if (i >= total) return;
  const int row = i / Np, col = i - row * Np;
  Ab[i] = (col < N) ? f2bf(A[(size_t)row * N + col]) : (unsigned short)0;
}

// ---------------------------------------------------------------------------
static inline void g1(hipStream_t s, const unsigned short* A, const unsigned short* B,
                      const float* bias, float* C, unsigned short* D,
                      int Kp, int Np, int ldc, int Nreal, int relu)
{
  GemmP p{};
  p.A = A; p.B0 = B; p.bias = bias; p.C = C; p.D0 = D;
  p.Kp = Kp; p.Np = Np; p.ldc = ldc; p.Nreal = Nreal; p.relu = relu;
  gemm_tpl<1><<<dim3(Np >> 6, MM >> 6), 256, 0, s>>>(p);
}

static inline void g3(hipStream_t s, const unsigned short* A, const unsigned short* B0,
                      const unsigned short* B1, const unsigned short* B2,
                      unsigned short* D0, unsigned short* D1, unsigned short* D2,
                      int Kp, int Np)
{
  GemmP p{};
  p.A = A; p.B0 = B0; p.B1 = B1; p.B2 = B2; p.D0 = D0; p.D1 = D1; p.D2 = D2;
  p.Kp = Kp; p.Np = Np; p.ldc = Np; p.Nreal = Np; p.relu = 0;
  gemm_tpl<3><<<dim3(3 * (Np >> 6), MM >> 6), 256, 0, s>>>(p);
}

extern "C" void kernel_launch(void* const* d_in, const int* in_sizes, int n_in,
                              void* d_out, int out_size, void* d_ws, size_t ws_size,
                              hipStream_t stream)
{
  (void)in_sizes; (void)n_in; (void)out_size; (void)ws_size;
  const float* dec_in = (const float*)d_in[0];
  const float* prev   = (const float*)d_in[1];
  const float* gk     = (const float*)d_in[6];
  const float* emb_w1 = (const float*)d_in[7];
  const float* emb_b1 = (const float*)d_in[8];
  const float* emb_w2 = (const float*)d_in[9];
  const float* emb_b2 = (const float*)d_in[10];
  const float* emb_w3 = (const float*)d_in[11];
  const float* emb_b3 = (const float*)d_in[12];
  const float* ln0_g  = (const float*)d_in[13];
  const float* ln0_b  = (const float*)d_in[14];
  const float* wq     = (const float*)d_in[15];
  const float* wk     = (const float*)d_in[16];
  const float* wv     = (const float*)d_in[17];
  const float* wo     = (const float*)d_in[18];
  const float* cq     = (const float*)d_in[19];
  const float* ck     = (const float*)d_in[20];
  const float* cv     = (const float*)d_in[21];
  const float* co     = (const float*)d_in[22];
  const float* ffn_w1 = (const float*)d_in[23];
  const float* ffn_w2 = (const float*)d_in[24];
  const float* ffn_b1 = (const float*)d_in[25];
  const float* ffn_b2 = (const float*)d_in[26];
  const float* ln1_g  = (const float*)d_in[27];
  const float* ln1_b  = (const float*)d_in[28];
  const float* ln2_g  = (const float*)d_in[29];
  const float* ln2_b  = (const float*)d_in[30];
  const float* ln3_g  = (const float*)d_in[31];
  const float* ln3_b  = (const float*)d_in[32];
  const float* p_w1   = (const float*)d_in[33];
  const float* p_b1   = (const float*)d_in[34];
  const float* p_w2   = (const float*)d_in[35];
  const float* p_b2   = (const float*)d_in[36];
  const float* p_w3   = (const float*)d_in[37];
  const float* p_b3   = (const float*)d_in[38];

  // ---- workspace carve ----
  char* wsp = (char*)d_ws;
  auto carve = [&](size_t bytes) { char* r = wsp; wsp += (bytes + 255) & ~(size_t)255; return r; };

  unsigned short* decb  = (unsigned short*)carve((size_t)MM * VP * 2);
  unsigned short* prevb = (unsigned short*)carve((size_t)MM * DD * 2);
  float*          hf    = (float*)carve((size_t)MM * DD * 4);
  unsigned short* hb    = (unsigned short*)carve((size_t)MM * DD * 2);
  float*          xf1   = (float*)carve((size_t)MM * DD * 4);
  unsigned short* tb1   = (unsigned short*)carve((size_t)MM * DFFN * 2);   // 8 MB
  unsigned short* Mbb   = tb1;                                   // alias: first 4 MB
  float*          xf2   = (float*)((char*)tb1 + (size_t)MM * SS * 2);      // alias: last 4 MB
  unsigned short* tb2a  = (unsigned short*)carve((size_t)MM * VP * 2);
  unsigned short* tb2b  = (unsigned short*)carve((size_t)MM * VP * 2);
  unsigned short* qb    = (unsigned short*)carve((size_t)MM * DD * 2);
  unsigned short* kb    = (unsigned short*)carve((size_t)MM * DD * 2);
  unsigned short* vb    = (unsigned short*)carve((size_t)MM * DD * 2);
  unsigned short* vbT   = (unsigned short*)carve((size_t)MM * DD * 2);
  float* kvs = (float*)carve((size_t)MM * 4);
  float* kve = (float*)carve((size_t)MM * 4);
  unsigned short* postabt = (unsigned short*)carve((size_t)DD * SS * 2);
  unsigned short* ew1t  = (unsigned short*)carve((size_t)VP * VP * 2);
  unsigned short* ew2t  = (unsigned short*)carve((size_t)VP * VP * 2);
  unsigned short* ew3t  = (unsigned short*)carve((size_t)DD * VP * 2);
  unsigned short* wqt   = (unsigned short*)carve((size_t)LL * DD * DD * 2);
  unsigned short* wkt   = (unsigned short*)carve((size_t)LL * DD * DD * 2);
  unsigned short* wvt   = (unsigned short*)carve((size_t)LL * DD * DD * 2);
  unsigned short* wot   = (unsigned short*)carve((size_t)LL * DD * DD * 2);
  unsigned short* cqt   = (unsigned short*)carve((size_t)LL * DD * DD * 2);
  unsigned short* ckt   = (unsigned short*)carve((size_t)LL * DD * DD * 2);
  unsigned short* cvt   = (unsigned short*)carve((size_t)LL * DD * DD * 2);
  unsigned short* cot   = (unsigned short*)carve((size_t)LL * DD * DD * 2);
  unsigned short* f1t   = (unsigned short*)carve((size_t)LL * DFFN * DD * 2);
  unsigned short* f2t   = (unsigned short*)carve((size_t)LL * DD * DFFN * 2);
  unsigned short* p1t   = (unsigned short*)carve((size_t)VP * DD * 2);
  unsigned short* p2t   = (unsigned short*)carve((size_t)VP * VP * 2);
  unsigned short* p3t   = (unsigned short*)carve((size_t)VP * VP * 2);
  unsigned short* ckall = (unsigned short*)carve((size_t)LL * MM * DD * 2);  // 12 MB
  unsigned short* cvall = (unsigned short*)carve((size_t)LL * MM * DD * 2);  // 12 MB
  unsigned short* cvbT  = (unsigned short*)carve((size_t)LL * MM * DD * 2);  // 12 MB

  const dim3 agrid(SS / 32, HH, BB);

  // ---- prep ----
  rowvalid_kernel<<<MM, 64, 0, stream>>>(dec_in, VV, kvs);
  rowvalid_kernel<<<MM, 64, 0, stream>>>(prev, DD, kve);
  aconv_kernel<<<(MM * VP + 255) / 256, 256, 0, stream>>>(dec_in, decb, VV, VP, MM * VP);
  aconv_kernel<<<(MM * DD + 255) / 256, 256, 0, stream>>>(prev, prevb, DD, DD, MM * DD);
  postable_kernel<<<(DD * SS + 255) / 256, 256, 0, stream>>>(postabt);
  gpec_kernel<<<(BB * SS * SS + 255) / 256, 256, 0, stream>>>(gk, Mbb);

  {
    WconvB wb{};
    wb.W[0] = wq; wb.W[1] = wk; wb.W[2] = wv; wb.W[3] = wo;
    wb.W[4] = cq; wb.W[5] = ck; wb.W[6] = cv; wb.W[7] = co;
    wb.WT[0] = wqt; wb.WT[1] = wkt; wb.WT[2] = wvt; wb.WT[3] = wot;
    wb.WT[4] = cqt; wb.WT[5] = ckt; wb.WT[6] = cvt; wb.WT[7] = cot;
    wconv8_kernel<<<dim3(8, 8, 8 * LL), 256, 0, stream>>>(wb);
  }
  wconv_kernel<<<dim3(9, 9, 1), 256, 0, stream>>>(emb_w1, ew1t, VV, VV, VP, VP);
  wconv_kernel<<<dim3(9, 9, 1), 256, 0, stream>>>(emb_w2, ew2t, VV, VV, VP, VP);
  wconv_kernel<<<dim3(8, 9, 1), 256, 0, stream>>>(emb_w3, ew3t, VV, DD, VP, DD);
  wconv_kernel<<<dim3(32, 8, LL), 256, 0, stream>>>(ffn_w1, f1t, DD, DFFN, DD, DFFN);
  wconv_kernel<<<dim3(8, 32, LL), 256, 0, stream>>>(ffn_w2, f2t, DFFN, DD, DFFN, DD);
  wconv_kernel<<<dim3(9, 8, 1), 256, 0, stream>>>(p_w1, p1t, DD, VV, DD, VP);
  wconv_kernel<<<dim3(9, 9, 1), 256, 0, stream>>>(p_w2, p2t, VV, VV, VP, VP);
  wconv_kernel<<<dim3(9, 9, 1), 256, 0, stream>>>(p_w3, p3t, VV, VV, VP, VP);

  // ---- all 6 layers' cross-attention K/V in one batched GEMM + transpose ----
  {
    GemmBat p{};
    p.A = prevb; p.Kp = DD; p.Np = DD;
    for (int i = 0; i < LL; ++i) {
      p.B[2 * i]     = ckt + (size_t)i * DD * DD;
      p.B[2 * i + 1] = cvt + (size_t)i * DD * DD;
      p.D[2 * i]     = ckall + (size_t)i * MM * DD;
      p.D[2 * i + 1] = cvall + (size_t)i * MM * DD;
    }
    gemm_bat<<<dim3(12 * (DD >> 6), MM >> 6), 256, 0, stream>>>(p);
    vtrans_kernel<<<dim3(16, 8, 2 * LL), 256, 0, stream>>>(cvall, cvbT);
  }

  // ---- embedding MLP + graph positional encoding ----
  g1(stream, decb, ew1t, emb_b1, nullptr, tb2a, VP, VP, VP, VV, 1);
  g1(stream, tb2a, ew2t, emb_b2, nullptr, tb2b, VP, VP, VP, VV, 1);
  g1(stream, tb2b, ew3t, emb_b3, xf1, nullptr, VP, DD, DD, DD, 0);
  g1(stream, Mbb, postabt, nullptr, xf2, nullptr, SS, DD, DD, DD, 0);
  addln_kernel<<<MM / 4, 256, 0, stream>>>(xf1, xf2, ln0_g, ln0_b, hf, hb);

  for (int i = 0; i < LL; ++i) {
    const size_t od = (size_t)i * DD * DD;
    // self attention
    g3(stream, hb, wqt + od, wkt + od, wvt + od, qb, kb, vb, DD, DD);
    vtrans_kernel<<<dim3(16, 8, 2), 256, 0, stream>>>(vb, vbT);
    attn_kernel<1><<<agrid, 128, 0, stream>>>(qb, kb, vbT, qb, kvs);
    g1(stream, qb, wot + od, nullptr, xf1, nullptr, DD, DD, DD, DD, 0);
    addln_kernel<<<MM / 4, 256, 0, stream>>>(hf, xf1, ln1_g + i * DD, ln1_b + i * DD, hf, hb);
    // cross attention (K/V precomputed)
    g1(stream, hb, cqt + od, nullptr, nullptr, qb, DD, DD, DD, DD, 0);
    attn_kernel<0><<<agrid, 128, 0, stream>>>(qb, ckall + (size_t)i * MM * DD,
                                              cvbT + (size_t)i * MM * DD, qb, kve);
    g1(stream, qb, cot + od, nullptr, xf1, nullptr, DD, DD, DD, DD, 0);
    addln_kernel<<<MM / 4, 256, 0, stream>>>(hf, xf1, ln2_g + i * DD, ln2_b + i * DD, hf, hb);
    // FFN
    g1(stream, hb, f1t + (size_t)i * DFFN * DD, ffn_b1 + i * DFFN, nullptr, tb1, DD, DFFN, DFFN, DFFN, 1);
    g1(stream, tb1, f2t + (size_t)i * DD * DFFN, ffn_b2 + i * DD, xf1, nullptr, DFFN, DD, DD, DD, 0);
    addln_kernel<<<MM / 4, 256, 0, stream>>>(hf, xf1, ln3_g + i * DD, ln3_b + i * DD, hf, hb);
  }

  // ---- output head ----
  g1(stream, hb, p1t, p_b1, nullptr, tb2a, DD, VP, VP, VV, 1);
  g1(stream, tb2a, p2t, p_b2, nullptr, tb2b, VP, VP, VP, VV, 1);
  g1(stream, tb2b, p3t, p_b3, (float*)d_out, nullptr, VP, VP, VV, VV, 0);
}